// Round 1
// baseline (47920.224 us; speedup 1.0000x reference)
//
#include <hip/hip_runtime.h>
#include <hip/hip_bf16.h>

// ---------------------------------------------------------------------------
// GRU, 2 layers, B=32, S=2048, D=H=512.
// Plan:
//   prep:  Wh -> WhP fp16-packed (K-pairs contiguous for v_dot2), Wi -> bf16
//   gemm:  ip = A @ Wi^T + bi   (bf16 MFMA 16x16x32, fp32 accum, ip fp32/bf16)
//   rec:   one WG per batch (32 WGs), whole 2048-step chain in-kernel,
//          fp16 dot2 matvec vs L2-resident WhP, h state fp32 in LDS.
//   y0 lives in d_out (overwritten by y1 later). ws: ip + converted weights.
// ---------------------------------------------------------------------------

typedef __bf16   bf16x8 __attribute__((ext_vector_type(8)));
typedef __bf16   bf16x4 __attribute__((ext_vector_type(4)));
typedef float    f32x4  __attribute__((ext_vector_type(4)));
typedef _Float16 f16x2  __attribute__((ext_vector_type(2)));

#define S_LEN 2048
#define BATCH 32
#define HID   512
#define G3    1536               // 3*H
#define MROWS (BATCH * S_LEN)    // 65536

__device__ inline float sigmoid_f(float x) { return 1.f / (1.f + __expf(-x)); }
__device__ inline float tanh_f(float x) {            // tanh = 1 - 2/(e^{2x}+1)
  float e = __expf(2.f * x);
  return 1.f - 2.f / (e + 1.f);
}

__device__ inline float fdot2f(f16x2 a, f16x2 b, float c) {
#if __has_builtin(__builtin_amdgcn_fdot2)
  return __builtin_amdgcn_fdot2(a, b, c, false);
#else
  return c + (float)a[0] * (float)b[0] + (float)a[1] * (float)b[1];
#endif
}

// ---- ip element store/load, templated on fp32 vs bf16 (ws-size fallback) ---
template <typename IPT>
__device__ inline void store_ip(IPT* p, float v) {
  if constexpr (sizeof(IPT) == 4) {
    *p = v;
  } else {
    *p = __builtin_bit_cast(unsigned short, (__bf16)v);
  }
}
template <typename IPT>
__device__ inline float4 load_ip4(const IPT* p) {
  if constexpr (sizeof(IPT) == 4) {
    return *(const float4*)p;
  } else {
    ushort4 u = *(const ushort4*)p;
    float4 r;
    r.x = __uint_as_float((unsigned)u.x << 16);
    r.y = __uint_as_float((unsigned)u.y << 16);
    r.z = __uint_as_float((unsigned)u.z << 16);
    r.w = __uint_as_float((unsigned)u.w << 16);
    return r;
  }
}

// ---------------------------------------------------------------------------
// prep kernels
// ---------------------------------------------------------------------------
// WhP[kp*1536 + c] = pack_f16x2(Wh[c][2kp], Wh[c][2kp+1]),  kp in [0,256)
__global__ void prep_whp(const float* __restrict__ Wh, unsigned int* __restrict__ out) {
  int idx = blockIdx.x * 256 + threadIdx.x;   // grid sized exactly 256*1536
  int kp = idx / G3, c = idx % G3;
  f16x2 p = { (_Float16)Wh[(size_t)c * HID + 2 * kp],
              (_Float16)Wh[(size_t)c * HID + 2 * kp + 1] };
  out[idx] = __builtin_bit_cast(unsigned int, p);
}

__global__ void prep_wib(const float* __restrict__ W, __bf16* __restrict__ o) {
  int i = blockIdx.x * 256 + threadIdx.x;     // grid sized exactly 1536*512
  o[i] = (__bf16)W[i];
}

// ---------------------------------------------------------------------------
// ip GEMM: C(M,1536) = A(M,512) @ Bw(1536,512)^T + bias.  64x64x64 tiles,
// 4 waves (2x2), each wave 32x32 via 2x2 mfma_f32_16x16x32_bf16 frags.
// ---------------------------------------------------------------------------
template <typename IPT>
__global__ __launch_bounds__(256) void gemm_ip(
    const float* __restrict__ A, const __bf16* __restrict__ Bw,
    const float* __restrict__ bias, IPT* __restrict__ C) {
  constexpr int K = 512;
  __shared__ __align__(16) __bf16 As[64][72];   // +8 pad keeps 16B alignment
  __shared__ __align__(16) __bf16 Bs[64][72];
  const int tid  = threadIdx.x;
  const int bm   = blockIdx.y, bn = blockIdx.x;
  const int lane = tid & 63,  wave = tid >> 6;
  const int wr   = wave >> 1, wc   = wave & 1;
  f32x4 acc[2][2] = {};
  const int r = tid >> 2, q = tid & 3;          // staging: 4 threads per row
  const float*  Arow = A  + (size_t)(bm * 64 + r) * K;
  const __bf16* Brow = Bw + (size_t)(bn * 64 + r) * K;

  for (int k0 = 0; k0 < K; k0 += 64) {
    // stage A (fp32 -> bf16): 4 float4 per thread
    const float4* as = (const float4*)(Arow + k0);
    #pragma unroll
    for (int i = 0; i < 4; ++i) {
      float4 v = as[q + 4 * i];
      bf16x4 p = { (__bf16)v.x, (__bf16)v.y, (__bf16)v.z, (__bf16)v.w };
      *(bf16x4*)&As[r][4 * (q + 4 * i)] = p;
    }
    // stage B (already bf16): 2 x 16B per thread
    const uint4* bs = (const uint4*)(Brow + k0);
    uint4* bd = (uint4*)&Bs[r][0];
    bd[q]     = bs[q];
    bd[q + 4] = bs[q + 4];
    __syncthreads();

    #pragma unroll
    for (int kk = 0; kk < 64; kk += 32) {
      const int kb = kk + 8 * (lane >> 4);      // 8 contiguous k per lane
      bf16x8 a0 = *(const bf16x8*)&As[wr * 32 +      (lane & 15)][kb];
      bf16x8 a1 = *(const bf16x8*)&As[wr * 32 + 16 + (lane & 15)][kb];
      bf16x8 b0 = *(const bf16x8*)&Bs[wc * 32 +      (lane & 15)][kb];
      bf16x8 b1 = *(const bf16x8*)&Bs[wc * 32 + 16 + (lane & 15)][kb];
      acc[0][0] = __builtin_amdgcn_mfma_f32_16x16x32_bf16(a0, b0, acc[0][0], 0, 0, 0);
      acc[0][1] = __builtin_amdgcn_mfma_f32_16x16x32_bf16(a0, b1, acc[0][1], 0, 0, 0);
      acc[1][0] = __builtin_amdgcn_mfma_f32_16x16x32_bf16(a1, b0, acc[1][0], 0, 0, 0);
      acc[1][1] = __builtin_amdgcn_mfma_f32_16x16x32_bf16(a1, b1, acc[1][1], 0, 0, 0);
    }
    __syncthreads();
  }

  // epilogue: C/D layout col = lane&15, row = (lane>>4)*4 + reg  [m89-verified]
  const int row0 = bm * 64 + wr * 32 + (lane >> 4) * 4;
  const int col0 = bn * 64 + wc * 32 + (lane & 15);
  #pragma unroll
  for (int fm = 0; fm < 2; ++fm)
    #pragma unroll
    for (int fn = 0; fn < 2; ++fn) {
      int n = col0 + fn * 16;
      float bv = bias[n];
      #pragma unroll
      for (int reg = 0; reg < 4; ++reg) {
        size_t off = (size_t)(row0 + fm * 16 + reg) * G3 + n;
        store_ip<IPT>(C + off, acc[fm][fn][reg] + bv);
      }
    }
}

// ---------------------------------------------------------------------------
// recurrence: one WG (384 threads) per batch. Thread c owns cols 4c..4c+3.
//   hp = h @ Wh^T + bh  via fp16 dot2; gates + h update in fp32.
// ---------------------------------------------------------------------------
template <typename IPT>
__global__ __launch_bounds__(384) void gru_rec(
    const IPT* __restrict__ ip,              // (B*S, 1536)
    const unsigned int* __restrict__ whp,    // (256, 1536) packed f16x2
    const float* __restrict__ bh,            // (1536)
    float* __restrict__ y,                   // (B*S, 512)
    float* __restrict__ hlast) {             // (B, 512) or nullptr
  __shared__ float    hp_sh[G3];
  __shared__ float    ipn_sh[HID];
  __shared__ float    hf_sh[HID];            // fp32 h state (carried)
  __shared__ _Float16 h_sh[HID];             // fp16 copy for dot2
  const int b = blockIdx.x;
  const int c = threadIdx.x;

  for (int k = c; k < HID; k += 384) { h_sh[k] = (_Float16)0.f; hf_sh[k] = 0.f; }
  const float4 bh4 = *(const float4*)(bh + 4 * c);
  const uint4* W   = (const uint4*)whp;      // [kp*384 + c] -> cols 4c..4c+3
  const f16x2* h2p = (const f16x2*)h_sh;
  __syncthreads();

  for (int t = 0; t < S_LEN; ++t) {
    const size_t row = (size_t)b * S_LEN + t;
    float4 ipv = load_ip4<IPT>(ip + row * G3 + 4 * c);  // issued early, used late
    float ax = bh4.x, ay = bh4.y, az = bh4.z, aw = bh4.w;
    #pragma unroll 8
    for (int kp = 0; kp < HID / 2; ++kp) {
      uint4 w  = W[kp * 384 + c];
      f16x2 hh = h2p[kp];
      ax = fdot2f(__builtin_bit_cast(f16x2, w.x), hh, ax);
      ay = fdot2f(__builtin_bit_cast(f16x2, w.y), hh, ay);
      az = fdot2f(__builtin_bit_cast(f16x2, w.z), hh, az);
      aw = fdot2f(__builtin_bit_cast(f16x2, w.w), hh, aw);
    }
    if (c < 256) {                           // r,z gates: fold ip in now
      float4 s; s.x = ax + ipv.x; s.y = ay + ipv.y; s.z = az + ipv.z; s.w = aw + ipv.w;
      *(float4*)(hp_sh + 4 * c) = s;
    } else {                                 // n gate: keep ip separate (r * hp_n)
      float4 s; s.x = ax; s.y = ay; s.z = az; s.w = aw;
      *(float4*)(hp_sh + 4 * c) = s;
      *(float4*)(ipn_sh + 4 * c - 1024) = ipv;
    }
    __syncthreads();
    for (int k = c; k < HID; k += 384) {
      float r  = sigmoid_f(hp_sh[k]);
      float z  = sigmoid_f(hp_sh[HID + k]);
      float n  = tanh_f(ipn_sh[k] + r * hp_sh[2 * HID + k]);
      float hy = (1.f - z) * n + z * hf_sh[k];
      y[row * HID + k] = hy;
      hf_sh[k] = hy;
      h_sh[k]  = (_Float16)hy;
      if (hlast && t == S_LEN - 1) hlast[b * HID + k] = hy;
    }
    __syncthreads();
  }
}

// ---------------------------------------------------------------------------
template <typename IPT>
static void run_all(const float* x,
                    const float* Wi0, const float* bi0, const float* Wh0, const float* bh0,
                    const float* Wi1, const float* bi1, const float* Wh1, const float* bh1,
                    float* out, char* ws, hipStream_t stream) {
  unsigned int* whp0 = (unsigned int*)(ws);
  unsigned int* whp1 = (unsigned int*)(ws + 1572864);
  __bf16* wi0b = (__bf16*)(ws + 3145728);
  __bf16* wi1b = (__bf16*)(ws + 4718592);
  IPT* ip = (IPT*)(ws + 6291456);
  float* y0    = out;                               // reuse d_out for y0
  float* hlast = out + (size_t)MROWS * HID;

  prep_whp<<<dim3(1536), dim3(256), 0, stream>>>(Wh0, whp0);
  prep_whp<<<dim3(1536), dim3(256), 0, stream>>>(Wh1, whp1);
  prep_wib<<<dim3(3072), dim3(256), 0, stream>>>(Wi0, wi0b);
  prep_wib<<<dim3(3072), dim3(256), 0, stream>>>(Wi1, wi1b);

  gemm_ip<IPT><<<dim3(24, 1024), dim3(256), 0, stream>>>(x, wi0b, bi0, ip);
  gru_rec<IPT><<<dim3(32), dim3(384), 0, stream>>>(ip, whp0, bh0, y0, (float*)nullptr);
  gemm_ip<IPT><<<dim3(24, 1024), dim3(256), 0, stream>>>(y0, wi1b, bi1, ip);
  gru_rec<IPT><<<dim3(32), dim3(384), 0, stream>>>(ip, whp1, bh1, out, hlast);
}

extern "C" void kernel_launch(void* const* d_in, const int* in_sizes, int n_in,
                              void* d_out, int out_size, void* d_ws, size_t ws_size,
                              hipStream_t stream) {
  const float* x   = (const float*)d_in[0];
  const float* Wi0 = (const float*)d_in[1];
  const float* bi0 = (const float*)d_in[2];
  const float* Wh0 = (const float*)d_in[3];
  const float* bh0 = (const float*)d_in[4];
  const float* Wi1 = (const float*)d_in[5];
  const float* bi1 = (const float*)d_in[6];
  const float* Wh1 = (const float*)d_in[7];
  const float* bh1 = (const float*)d_in[8];
  float* out = (float*)d_out;
  char*  ws  = (char*)d_ws;

  const size_t need_f32 = 6291456ull + (size_t)MROWS * G3 * 4;   // ~409 MB
  if (ws_size >= need_f32) {
    run_all<float>(x, Wi0, bi0, Wh0, bh0, Wi1, bi1, Wh1, bh1, out, ws, stream);
  } else {
    run_all<unsigned short>(x, Wi0, bi0, Wh0, bh0, Wi1, bi1, Wh1, bh1, out, ws, stream);
  }
}

// Round 2
// 28945.865 us; speedup vs baseline: 1.6555x; 1.6555x over previous
//
#include <hip/hip_runtime.h>
#include <hip/hip_bf16.h>

// ---------------------------------------------------------------------------
// GRU, 2 layers, B=32, S=2048, D=H=512.
//   gemm:  ip = A @ Wi^T + bi   (bf16 MFMA, fp32 accum)  [unchanged, works]
//   rec:   NEW: 16 WGs col-split the 1536 gate-cols; M=32 batches via MFMA f16.
//          Weight slice (96 KB) register-resident as pre-packed B-fragments.
//          Per-step cross-WG h exchange via LLC-coherent (agent-scope) ops +
//          count flag; double-buffered Hbuf; flags memset each launch.
// ---------------------------------------------------------------------------

typedef __bf16    bf16x8 __attribute__((ext_vector_type(8)));
typedef __bf16    bf16x4 __attribute__((ext_vector_type(4)));
typedef float     f32x4  __attribute__((ext_vector_type(4)));
typedef _Float16  f16x2  __attribute__((ext_vector_type(2)));
typedef _Float16  f16x8  __attribute__((ext_vector_type(8)));

#define S_LEN 2048
#define BATCH 32
#define HID   512
#define G3    1536
#define MROWS (BATCH * S_LEN)
#define NWG   16                 // rec col-split WGs

__device__ inline float sigmoid_f(float x) { return 1.f / (1.f + __expf(-x)); }
__device__ inline float tanh_f(float x) {
  float e = __expf(2.f * x);
  return 1.f - 2.f / (e + 1.f);
}

// ---- ip element store/load, templated on fp32 vs bf16 (ws-size fallback) ---
template <typename IPT>
__device__ inline void store_ip(IPT* p, float v) {
  if constexpr (sizeof(IPT) == 4) *p = v;
  else *p = __builtin_bit_cast(unsigned short, (__bf16)v);
}
template <typename IPT>
__device__ inline float4 load_ip4(const IPT* p) {
  if constexpr (sizeof(IPT) == 4) {
    return *(const float4*)p;
  } else {
    ushort4 u = *(const ushort4*)p;
    float4 r;
    r.x = __uint_as_float((unsigned)u.x << 16);
    r.y = __uint_as_float((unsigned)u.y << 16);
    r.z = __uint_as_float((unsigned)u.z << 16);
    r.w = __uint_as_float((unsigned)u.w << 16);
    return r;
  }
}

// ---------------------------------------------------------------------------
// prep: Wi fp32 -> bf16 (for ip GEMM)
// ---------------------------------------------------------------------------
__global__ void prep_wib(const float* __restrict__ W, __bf16* __restrict__ o) {
  int i = blockIdx.x * 256 + threadIdx.x;     // grid = 1536*512/256
  o[i] = (__bf16)W[i];
}

// ---------------------------------------------------------------------------
// prep: Wh fp32 -> per-WG register-resident B-fragment order (f16 packed).
// Layout (dwords): idx = p*24576 + set*12288 + frag*256 + lane*4 + d
//   frag = nt*16 + ks ; N-tile jt = set*3+nt ; j = jt*16 + (lane&15) in [0,96)
//   gate g = j>>5, klocal = j&31 -> Wh row = g*512 + p*32 + klocal
//   k = ks*32 + 8*(lane>>4) + 2*d  (f16 pair k, k+1)
// ---------------------------------------------------------------------------
__global__ void prep_bfrag(const float* __restrict__ Wh, unsigned int* __restrict__ out) {
  int idx = blockIdx.x * 256 + threadIdx.x;   // grid = 393216/256 = 1536
  int p    = idx / 24576;
  int r    = idx % 24576;
  int set  = r / 12288;
  int r2   = r % 12288;
  int frag = r2 / 256;
  int lq   = r2 % 256;
  int l    = lq >> 2, d = lq & 3;
  int nt   = frag >> 4, ks = frag & 15;
  int j    = (set * 3 + nt) * 16 + (l & 15);
  int g    = j >> 5, kl = j & 31;
  int row  = g * 512 + p * 32 + kl;
  int k    = ks * 32 + 8 * (l >> 4) + 2 * d;
  f16x2 pk = { (_Float16)Wh[(size_t)row * HID + k],
               (_Float16)Wh[(size_t)row * HID + k + 1] };
  out[idx] = __builtin_bit_cast(unsigned int, pk);
}

// ---------------------------------------------------------------------------
// ip GEMM (unchanged from round 1, verified): C(M,1536)=A(M,512)@Bw(1536,512)^T+b
// ---------------------------------------------------------------------------
template <typename IPT>
__global__ __launch_bounds__(256) void gemm_ip(
    const float* __restrict__ A, const __bf16* __restrict__ Bw,
    const float* __restrict__ bias, IPT* __restrict__ C) {
  constexpr int K = 512;
  __shared__ __align__(16) __bf16 As[64][72];
  __shared__ __align__(16) __bf16 Bs[64][72];
  const int tid  = threadIdx.x;
  const int bm   = blockIdx.y, bn = blockIdx.x;
  const int lane = tid & 63,  wave = tid >> 6;
  const int wr   = wave >> 1, wc   = wave & 1;
  f32x4 acc[2][2] = {};
  const int r = tid >> 2, q = tid & 3;
  const float*  Arow = A  + (size_t)(bm * 64 + r) * K;
  const __bf16* Brow = Bw + (size_t)(bn * 64 + r) * K;

  for (int k0 = 0; k0 < K; k0 += 64) {
    const float4* as = (const float4*)(Arow + k0);
    #pragma unroll
    for (int i = 0; i < 4; ++i) {
      float4 v = as[q + 4 * i];
      bf16x4 pkt = { (__bf16)v.x, (__bf16)v.y, (__bf16)v.z, (__bf16)v.w };
      *(bf16x4*)&As[r][4 * (q + 4 * i)] = pkt;
    }
    const uint4* bs = (const uint4*)(Brow + k0);
    uint4* bd = (uint4*)&Bs[r][0];
    bd[q]     = bs[q];
    bd[q + 4] = bs[q + 4];
    __syncthreads();

    #pragma unroll
    for (int kk = 0; kk < 64; kk += 32) {
      const int kb = kk + 8 * (lane >> 4);
      bf16x8 a0 = *(const bf16x8*)&As[wr * 32 +      (lane & 15)][kb];
      bf16x8 a1 = *(const bf16x8*)&As[wr * 32 + 16 + (lane & 15)][kb];
      bf16x8 b0 = *(const bf16x8*)&Bs[wc * 32 +      (lane & 15)][kb];
      bf16x8 b1 = *(const bf16x8*)&Bs[wc * 32 + 16 + (lane & 15)][kb];
      acc[0][0] = __builtin_amdgcn_mfma_f32_16x16x32_bf16(a0, b0, acc[0][0], 0, 0, 0);
      acc[0][1] = __builtin_amdgcn_mfma_f32_16x16x32_bf16(a0, b1, acc[0][1], 0, 0, 0);
      acc[1][0] = __builtin_amdgcn_mfma_f32_16x16x32_bf16(a1, b0, acc[1][0], 0, 0, 0);
      acc[1][1] = __builtin_amdgcn_mfma_f32_16x16x32_bf16(a1, b1, acc[1][1], 0, 0, 0);
    }
    __syncthreads();
  }

  const int row0 = bm * 64 + wr * 32 + (lane >> 4) * 4;
  const int col0 = bn * 64 + wc * 32 + (lane & 15);
  #pragma unroll
  for (int fm = 0; fm < 2; ++fm)
    #pragma unroll
    for (int fn = 0; fn < 2; ++fn) {
      int n = col0 + fn * 16;
      float bv = bias[n];
      #pragma unroll
      for (int reg = 0; reg < 4; ++reg) {
        size_t off = (size_t)(row0 + fm * 16 + reg) * G3 + n;
        store_ip<IPT>(C + off, acc[fm][fn][reg] + bv);
      }
    }
}

// ---------------------------------------------------------------------------
// recurrence: 16 WGs x 256 threads. WG p owns gate-cols {k,512+k,1024+k},
// k in [32p,32p+32), for ALL 32 batches. Weights register-resident.
// Cross-WG h exchange via agent-scope (LLC) loads/stores + count flag.
// ---------------------------------------------------------------------------
template <typename IPT>
__global__ __launch_bounds__(256, 1) void gru_rec2(
    const IPT* __restrict__ ip,            // (B*S, 1536)
    const uint4* __restrict__ bfrag,       // packed B-frags
    const float* __restrict__ bh,          // (1536)
    float* __restrict__ y,                 // (B*S, 512)
    float* __restrict__ hlast,             // (B,512) or nullptr
    unsigned int* __restrict__ hbuf,       // f16 h, 2 x 32 x 512 (as dwords)
    unsigned int* __restrict__ fl) {       // 2048 counters (zeroed by memset)
  __shared__ __align__(16) unsigned char Hs[32 * 1024];  // f16 [32][512], swizzled
  __shared__ float hp[96 * 33];                          // padded [96][33]
  __shared__ float hf[32 * 32];                          // fp32 master h slice
  const int p = blockIdx.x, tid = threadIdx.x;
  const int lane = tid & 63, wave = tid >> 6;
  const int set = wave & 1, m = wave >> 1;

  // ---- load register-resident B-fragments (48 x uint4 = 192 VGPRs) ----
  uint4 wf[48];
  {
    const uint4* bsrc = bfrag + ((size_t)(p * 2 + set) * 48) * 64 + lane;
    #pragma unroll
    for (int i = 0; i < 48; ++i) wf[i] = bsrc[i * 64];
  }

  // ---- update-phase constants ----
  const int ub = tid >> 3;                 // batch 0..31
  const int uk = (tid & 7) * 4;            // local col base 0..28
  const int colg = p * 32 + uk;            // global h col base
  const float4 bhr = *(const float4*)(bh + colg);
  const float4 bhz = *(const float4*)(bh + 512 + colg);
  const float4 bhn = *(const float4*)(bh + 1024 + colg);

  for (int i = tid; i < 1024; i += 256) hf[i] = 0.f;

  for (int t = 0; t < S_LEN; ++t) {
    // ---- wait for step t-1 outputs ----
    if (t > 0 && tid == 0) {
      while (__hip_atomic_load(fl + (t - 1), __ATOMIC_RELAXED,
                               __HIP_MEMORY_SCOPE_AGENT) < NWG)
        __builtin_amdgcn_s_sleep(2);
    }
    __syncthreads();

    // ---- stage H (f16 32x512) from hbuf[t&1] via LLC-coherent loads ----
    {
      const unsigned int* src = hbuf + (t & 1) * 8192;
      const int b = tid >> 3, kp = tid & 7;
      const int swz = (b & 7) << 4;
      #pragma unroll
      for (int c = 0; c < 8; ++c) {
        const int w0 = b * 256 + kp * 32 + c * 4;
        uint4 v;
        v.x = __hip_atomic_load(src + w0 + 0, __ATOMIC_RELAXED, __HIP_MEMORY_SCOPE_AGENT);
        v.y = __hip_atomic_load(src + w0 + 1, __ATOMIC_RELAXED, __HIP_MEMORY_SCOPE_AGENT);
        v.z = __hip_atomic_load(src + w0 + 2, __ATOMIC_RELAXED, __HIP_MEMORY_SCOPE_AGENT);
        v.w = __hip_atomic_load(src + w0 + 3, __ATOMIC_RELAXED, __HIP_MEMORY_SCOPE_AGENT);
        const int kbyte = kp * 128 + c * 16;
        *(uint4*)&Hs[b * 1024 + (kbyte ^ swz)] = v;
      }
    }

    // ---- prefetch ip for the update phase (used after MFMA) ----
    const size_t iprow = (size_t)ub * S_LEN + t;
    float4 ipr = load_ip4<IPT>(ip + iprow * G3 + colg);
    float4 ipz = load_ip4<IPT>(ip + iprow * G3 + 512 + colg);
    float4 ipn = load_ip4<IPT>(ip + iprow * G3 + 1024 + colg);
    __syncthreads();

    // ---- MFMA: hp-slice(32 x 96) = H(32x512) @ Ws^T(512x96) ----
    f32x4 acc0 = {}, acc1 = {}, acc2 = {};
    {
      const int row = m * 16 + (lane & 15);
      const int swz = (row & 7) << 4;
      const unsigned char* base = &Hs[row * 1024];
      #pragma unroll
      for (int ks = 0; ks < 16; ++ks) {
        const int kbyte = ks * 64 + 16 * (lane >> 4);
        f16x8 a = *(const f16x8*)(base + (kbyte ^ swz));
        acc0 = __builtin_amdgcn_mfma_f32_16x16x32_f16(a, __builtin_bit_cast(f16x8, wf[ks]),      acc0, 0, 0, 0);
        acc1 = __builtin_amdgcn_mfma_f32_16x16x32_f16(a, __builtin_bit_cast(f16x8, wf[16 + ks]), acc1, 0, 0, 0);
        acc2 = __builtin_amdgcn_mfma_f32_16x16x32_f16(a, __builtin_bit_cast(f16x8, wf[32 + ks]), acc2, 0, 0, 0);
      }
    }
    // C/D layout: col=lane&15 (j within tile), row=(lane>>4)*4+reg (batch)
    {
      const int j0 = (set * 3) * 16 + (lane & 15);
      const int bt = m * 16 + (lane >> 4) * 4;
      #pragma unroll
      for (int q = 0; q < 4; ++q) {
        hp[(j0 +  0) * 33 + bt + q] = acc0[q];
        hp[(j0 + 16) * 33 + bt + q] = acc1[q];
        hp[(j0 + 32) * 33 + bt + q] = acc2[q];
      }
    }
    __syncthreads();

    // ---- gate + h update; thread -> (batch ub, cols uk..uk+3) ----
    {
      float hyv[4];
      unsigned short hx[4];
      #pragma unroll
      for (int c2 = 0; c2 < 4; ++c2) {
        const int kk = uk + c2;
        float pr = hp[kk * 33 + ub]        + (&bhr.x)[c2] + (&ipr.x)[c2];
        float pz = hp[(32 + kk) * 33 + ub] + (&bhz.x)[c2] + (&ipz.x)[c2];
        float pn = hp[(64 + kk) * 33 + ub] + (&bhn.x)[c2];
        float rr = sigmoid_f(pr);
        float zz = sigmoid_f(pz);
        float nn = tanh_f((&ipn.x)[c2] + rr * pn);
        float h0 = hf[ub * 32 + kk];
        float hy = (1.f - zz) * nn + zz * h0;
        hf[ub * 32 + kk] = hy;
        hyv[c2] = hy;
        hx[c2] = __builtin_bit_cast(unsigned short, (_Float16)hy);
      }
      float4 yo = { hyv[0], hyv[1], hyv[2], hyv[3] };
      *(float4*)(y + iprow * HID + colg) = yo;
      if (hlast && t == S_LEN - 1)
        *(float4*)(hlast + (size_t)ub * HID + colg) = yo;
      // publish f16 h to hbuf[(t+1)&1] (LLC-coherent stores)
      unsigned int* dst = hbuf + ((t + 1) & 1) * 8192 + ub * 256 + (colg >> 1);
      const unsigned w0 = (unsigned)hx[0] | ((unsigned)hx[1] << 16);
      const unsigned w1 = (unsigned)hx[2] | ((unsigned)hx[3] << 16);
      __hip_atomic_store(dst + 0, w0, __ATOMIC_RELAXED, __HIP_MEMORY_SCOPE_AGENT);
      __hip_atomic_store(dst + 1, w1, __ATOMIC_RELAXED, __HIP_MEMORY_SCOPE_AGENT);
    }
    // drain this wave's stores, barrier all waves, then signal step done
    asm volatile("s_waitcnt vmcnt(0)" ::: "memory");
    __syncthreads();
    if (tid == 0)
      __hip_atomic_fetch_add(fl + t, 1u, __ATOMIC_RELAXED, __HIP_MEMORY_SCOPE_AGENT);
  }
}

// ---------------------------------------------------------------------------
// ws layout (bytes)
// ---------------------------------------------------------------------------
#define BF0_OFF 0ull
#define BF1_OFF 1572864ull
#define WI0_OFF 3145728ull
#define WI1_OFF 4718592ull
#define HB_OFF  6291456ull        // 65536 B (f16 h double buffer)
#define FL_OFF  6356992ull        // 16384 B (2 x 2048 counters)
#define IP_OFF  8388608ull

template <typename IPT>
static void run_all(const float* x,
                    const float* Wi0, const float* bi0, const float* Wh0, const float* bh0,
                    const float* Wi1, const float* bi1, const float* Wh1, const float* bh1,
                    float* out, char* ws, hipStream_t stream) {
  unsigned int* bf0  = (unsigned int*)(ws + BF0_OFF);
  unsigned int* bf1  = (unsigned int*)(ws + BF1_OFF);
  __bf16* wi0b = (__bf16*)(ws + WI0_OFF);
  __bf16* wi1b = (__bf16*)(ws + WI1_OFF);
  unsigned int* hbuf = (unsigned int*)(ws + HB_OFF);
  unsigned int* fl   = (unsigned int*)(ws + FL_OFF);
  IPT* ip = (IPT*)(ws + IP_OFF);
  float* y0    = out;
  float* hlast = out + (size_t)MROWS * HID;

  // zero h double-buffer + both layers' flags (graph-replay determinism)
  hipMemsetAsync(ws + HB_OFF, 0, 65536 + 16384, stream);

  prep_bfrag<<<dim3(1536), dim3(256), 0, stream>>>(Wh0, bf0);
  prep_bfrag<<<dim3(1536), dim3(256), 0, stream>>>(Wh1, bf1);
  prep_wib<<<dim3(3072), dim3(256), 0, stream>>>(Wi0, wi0b);
  prep_wib<<<dim3(3072), dim3(256), 0, stream>>>(Wi1, wi1b);

  gemm_ip<IPT><<<dim3(24, 1024), dim3(256), 0, stream>>>(x, wi0b, bi0, ip);
  gru_rec2<IPT><<<dim3(NWG), dim3(256), 0, stream>>>(ip, (const uint4*)bf0, bh0,
                                                     y0, (float*)nullptr, hbuf, fl);
  hipMemsetAsync(ws + HB_OFF, 0, 65536, stream);   // re-zero h for layer 1
  gemm_ip<IPT><<<dim3(24, 1024), dim3(256), 0, stream>>>(y0, wi1b, bi1, ip);
  gru_rec2<IPT><<<dim3(NWG), dim3(256), 0, stream>>>(ip, (const uint4*)bf1, bh1,
                                                     out, hlast, hbuf, fl + 2048);
}

extern "C" void kernel_launch(void* const* d_in, const int* in_sizes, int n_in,
                              void* d_out, int out_size, void* d_ws, size_t ws_size,
                              hipStream_t stream) {
  const float* x   = (const float*)d_in[0];
  const float* Wi0 = (const float*)d_in[1];
  const float* bi0 = (const float*)d_in[2];
  const float* Wh0 = (const float*)d_in[3];
  const float* bh0 = (const float*)d_in[4];
  const float* Wi1 = (const float*)d_in[5];
  const float* bi1 = (const float*)d_in[6];
  const float* Wh1 = (const float*)d_in[7];
  const float* bh1 = (const float*)d_in[8];
  float* out = (float*)d_out;
  char*  ws  = (char*)d_ws;

  const size_t need_f32 = IP_OFF + (size_t)MROWS * G3 * 4;
  if (ws_size >= need_f32) {
    run_all<float>(x, Wi0, bi0, Wh0, bh0, Wi1, bi1, Wh1, bh1, out, ws, stream);
  } else {
    run_all<unsigned short>(x, Wi0, bi0, Wh0, bh0, Wi1, bi1, Wh1, bh1, out, ws, stream);
  }
}

// Round 3
// 19264.423 us; speedup vs baseline: 2.4875x; 1.5026x over previous
//
#include <hip/hip_runtime.h>
#include <hip/hip_bf16.h>

// ---------------------------------------------------------------------------
// GRU, 2 layers, B=32, S=2048, D=H=512.
//   gemm:  ip = A @ Wi^T + bi   (bf16 MFMA, fp32 accum)  [unchanged, verified]
//   rec:   16 WGs col-split the 1536 gate-cols; M=32 batches via MFMA f16.
//          Weight slice (96 KB) register-resident as pre-packed B-fragments.
//          Round 3: A-fragments loaded DIRECTLY from LLC hbuf via coherent
//          asm dwordx4 (sc0 sc1) — no LDS staging; per-WG flag slots; 8B
//          h publish; ip prefetch before poll.
// ---------------------------------------------------------------------------

typedef __bf16    bf16x8 __attribute__((ext_vector_type(8)));
typedef __bf16    bf16x4 __attribute__((ext_vector_type(4)));
typedef float     f32x4  __attribute__((ext_vector_type(4)));
typedef _Float16  f16x2  __attribute__((ext_vector_type(2)));
typedef _Float16  f16x8  __attribute__((ext_vector_type(8)));

#define S_LEN 2048
#define BATCH 32
#define HID   512
#define G3    1536
#define MROWS (BATCH * S_LEN)
#define NWG   16

__device__ inline float sigmoid_f(float x) { return 1.f / (1.f + __expf(-x)); }
__device__ inline float tanh_f(float x) {
  float e = __expf(2.f * x);
  return 1.f - 2.f / (e + 1.f);
}

// ---- ip element store/load, templated on fp32 vs bf16 (ws-size fallback) ---
template <typename IPT>
__device__ inline void store_ip(IPT* p, float v) {
  if constexpr (sizeof(IPT) == 4) *p = v;
  else *p = __builtin_bit_cast(unsigned short, (__bf16)v);
}
template <typename IPT>
__device__ inline float4 load_ip4(const IPT* p) {
  if constexpr (sizeof(IPT) == 4) {
    return *(const float4*)p;
  } else {
    ushort4 u = *(const ushort4*)p;
    float4 r;
    r.x = __uint_as_float((unsigned)u.x << 16);
    r.y = __uint_as_float((unsigned)u.y << 16);
    r.z = __uint_as_float((unsigned)u.z << 16);
    r.w = __uint_as_float((unsigned)u.w << 16);
    return r;
  }
}

// ---------------------------------------------------------------------------
// prep: Wi fp32 -> bf16
// ---------------------------------------------------------------------------
__global__ void prep_wib(const float* __restrict__ W, __bf16* __restrict__ o) {
  int i = blockIdx.x * 256 + threadIdx.x;
  o[i] = (__bf16)W[i];
}

// ---------------------------------------------------------------------------
// prep: Wh fp32 -> per-WG register-resident B-fragment order (f16 packed).
//   idx = p*24576 + set*12288 + frag*256 + lane*4 + d
//   frag = nt*16 + ks ; j = set*48 + nt*16 + (lane&15) in [0,96)
//   gate g = j>>5, klocal = j&31 -> Wh row = g*512 + p*32 + klocal
//   k = ks*32 + 8*(lane>>4) + 2*d
// ---------------------------------------------------------------------------
__global__ void prep_bfrag(const float* __restrict__ Wh, unsigned int* __restrict__ out) {
  int idx = blockIdx.x * 256 + threadIdx.x;   // grid = 393216/256 = 1536
  int p    = idx / 24576;
  int r    = idx % 24576;
  int set  = r / 12288;
  int r2   = r % 12288;
  int frag = r2 / 256;
  int lq   = r2 % 256;
  int l    = lq >> 2, d = lq & 3;
  int nt   = frag >> 4, ks = frag & 15;
  int j    = set * 48 + nt * 16 + (l & 15);
  int g    = j >> 5, kl = j & 31;
  int row  = g * 512 + p * 32 + kl;
  int k    = ks * 32 + 8 * (l >> 4) + 2 * d;
  f16x2 pk = { (_Float16)Wh[(size_t)row * HID + k],
               (_Float16)Wh[(size_t)row * HID + k + 1] };
  out[idx] = __builtin_bit_cast(unsigned int, pk);
}

// ---------------------------------------------------------------------------
// ip GEMM (verified): C(M,1536)=A(M,512)@Bw(1536,512)^T + bias
// ---------------------------------------------------------------------------
template <typename IPT>
__global__ __launch_bounds__(256) void gemm_ip(
    const float* __restrict__ A, const __bf16* __restrict__ Bw,
    const float* __restrict__ bias, IPT* __restrict__ C) {
  constexpr int K = 512;
  __shared__ __align__(16) __bf16 As[64][72];
  __shared__ __align__(16) __bf16 Bs[64][72];
  const int tid  = threadIdx.x;
  const int bm   = blockIdx.y, bn = blockIdx.x;
  const int lane = tid & 63,  wave = tid >> 6;
  const int wr   = wave >> 1, wc   = wave & 1;
  f32x4 acc[2][2] = {};
  const int r = tid >> 2, q = tid & 3;
  const float*  Arow = A  + (size_t)(bm * 64 + r) * K;
  const __bf16* Brow = Bw + (size_t)(bn * 64 + r) * K;

  for (int k0 = 0; k0 < K; k0 += 64) {
    const float4* as = (const float4*)(Arow + k0);
    #pragma unroll
    for (int i = 0; i < 4; ++i) {
      float4 v = as[q + 4 * i];
      bf16x4 pkt = { (__bf16)v.x, (__bf16)v.y, (__bf16)v.z, (__bf16)v.w };
      *(bf16x4*)&As[r][4 * (q + 4 * i)] = pkt;
    }
    const uint4* bs = (const uint4*)(Brow + k0);
    uint4* bd = (uint4*)&Bs[r][0];
    bd[q]     = bs[q];
    bd[q + 4] = bs[q + 4];
    __syncthreads();

    #pragma unroll
    for (int kk = 0; kk < 64; kk += 32) {
      const int kb = kk + 8 * (lane >> 4);
      bf16x8 a0 = *(const bf16x8*)&As[wr * 32 +      (lane & 15)][kb];
      bf16x8 a1 = *(const bf16x8*)&As[wr * 32 + 16 + (lane & 15)][kb];
      bf16x8 b0 = *(const bf16x8*)&Bs[wc * 32 +      (lane & 15)][kb];
      bf16x8 b1 = *(const bf16x8*)&Bs[wc * 32 + 16 + (lane & 15)][kb];
      acc[0][0] = __builtin_amdgcn_mfma_f32_16x16x32_bf16(a0, b0, acc[0][0], 0, 0, 0);
      acc[0][1] = __builtin_amdgcn_mfma_f32_16x16x32_bf16(a0, b1, acc[0][1], 0, 0, 0);
      acc[1][0] = __builtin_amdgcn_mfma_f32_16x16x32_bf16(a1, b0, acc[1][0], 0, 0, 0);
      acc[1][1] = __builtin_amdgcn_mfma_f32_16x16x32_bf16(a1, b1, acc[1][1], 0, 0, 0);
    }
    __syncthreads();
  }

  const int row0 = bm * 64 + wr * 32 + (lane >> 4) * 4;
  const int col0 = bn * 64 + wc * 32 + (lane & 15);
  #pragma unroll
  for (int fm = 0; fm < 2; ++fm)
    #pragma unroll
    for (int fn = 0; fn < 2; ++fn) {
      int n = col0 + fn * 16;
      float bv = bias[n];
      #pragma unroll
      for (int reg = 0; reg < 4; ++reg) {
        size_t off = (size_t)(row0 + fm * 16 + reg) * G3 + n;
        store_ip<IPT>(C + off, acc[fm][fn][reg] + bv);
      }
    }
}

// ---------------------------------------------------------------------------
// recurrence v3: 16 WGs x 256 threads. WG p owns gate-cols {k,512+k,1024+k},
// k in [32p,32p+32). A-frags direct from LLC hbuf (sc0 sc1), weights in regs.
// ---------------------------------------------------------------------------
template <typename IPT>
__global__ __launch_bounds__(256, 1) void gru_rec3(
    const IPT* __restrict__ ip,                 // (B*S, 1536)
    const uint4* __restrict__ bfrag,            // packed B-frags
    const float* __restrict__ bh,               // (1536)
    float* __restrict__ y,                      // (B*S, 512)
    float* __restrict__ hlast,                  // (B,512) or nullptr
    unsigned long long* __restrict__ hbuf,      // f16 h: [2][32][128] x 8B
    unsigned int* __restrict__ fl) {            // [S_LEN][NWG], memset 0
  __shared__ float hp[96 * 33];                 // padded [96][33]
  __shared__ float hf[32 * 32];                 // fp32 master h slice
  const int p = blockIdx.x, tid = threadIdx.x;
  const int lane = tid & 63, wave = tid >> 6;
  const int set = wave & 1, m = wave >> 1;

  // ---- register-resident B-fragments (48 x uint4 = 192 VGPRs) ----
  uint4 wf[48];
  {
    const uint4* bsrc = bfrag + ((size_t)(p * 2 + set) * 48) * 64 + lane;
    #pragma unroll
    for (int i = 0; i < 48; ++i) wf[i] = bsrc[i * 64];
  }

  // ---- update-phase constants ----
  const int ub = tid >> 3;                 // batch 0..31
  const int uk = (tid & 7) * 4;            // local col base
  const int colg = p * 32 + uk;            // global h col base
  const float4 bhr = *(const float4*)(bh + colg);
  const float4 bhz = *(const float4*)(bh + 512 + colg);
  const float4 bhn = *(const float4*)(bh + 1024 + colg);

  for (int i = tid; i < 1024; i += 256) hf[i] = 0.f;
  __syncthreads();

  // A-frag source address pieces: row = m*16 + (lane&15), 64B group by lane>>4
  const int arow = m * 16 + (lane & 15);
  const int abyte = arow * 1024 + 16 * (lane >> 4);

  for (int t = 0; t < S_LEN; ++t) {
    // ---- 1. issue ip loads (independent of flags) ----
    const size_t iprow = (size_t)ub * S_LEN + t;
    float4 ipr = load_ip4<IPT>(ip + iprow * G3 + colg);
    float4 ipz = load_ip4<IPT>(ip + iprow * G3 + 512 + colg);
    float4 ipn = load_ip4<IPT>(ip + iprow * G3 + 1024 + colg);
    __builtin_amdgcn_sched_barrier(0);

    // ---- 2. poll step t-1 flags (all lanes; one 64B line) ----
    if (t > 0) {
      const unsigned int* f = fl + (size_t)(t - 1) * NWG;
      while (true) {
        unsigned v = (lane < NWG)
            ? __hip_atomic_load(f + lane, __ATOMIC_RELAXED, __HIP_MEMORY_SCOPE_AGENT)
            : 1u;
        if (__all(v != 0)) break;
        __builtin_amdgcn_s_sleep(1);
      }
    }
    __builtin_amdgcn_sched_barrier(0);

    // ---- 3. A-fragments direct from LLC (coherent 16B loads) ----
    const char* hb = (const char*)hbuf + (t & 1) * 32768 + abyte;
    uint4 af[16];
    #pragma unroll
    for (int ks = 0; ks < 16; ++ks)
      asm volatile("global_load_dwordx4 %0, %1, off offset:%2 sc0 sc1"
                   : "=v"(af[ks]) : "v"(hb), "i"(ks * 64) : "memory");
    asm volatile("s_waitcnt vmcnt(0)" ::: "memory");
    __builtin_amdgcn_sched_barrier(0);

    // ---- 4. MFMA: hp-slice(32 x 96) = H(32x512) @ Ws^T(512x96) ----
    f32x4 acc0 = {}, acc1 = {}, acc2 = {};
    #pragma unroll
    for (int ks = 0; ks < 16; ++ks) {
      f16x8 a = __builtin_bit_cast(f16x8, af[ks]);
      acc0 = __builtin_amdgcn_mfma_f32_16x16x32_f16(a, __builtin_bit_cast(f16x8, wf[ks]),      acc0, 0, 0, 0);
      acc1 = __builtin_amdgcn_mfma_f32_16x16x32_f16(a, __builtin_bit_cast(f16x8, wf[16 + ks]), acc1, 0, 0, 0);
      acc2 = __builtin_amdgcn_mfma_f32_16x16x32_f16(a, __builtin_bit_cast(f16x8, wf[32 + ks]), acc2, 0, 0, 0);
    }
    // C/D layout: col=lane&15 (j), row=(lane>>4)*4+reg (batch)
    {
      const int j0 = set * 48 + (lane & 15);
      const int bt = m * 16 + (lane >> 4) * 4;
      #pragma unroll
      for (int q = 0; q < 4; ++q) {
        hp[(j0 +  0) * 33 + bt + q] = acc0[q];
        hp[(j0 + 16) * 33 + bt + q] = acc1[q];
        hp[(j0 + 32) * 33 + bt + q] = acc2[q];
      }
    }
    __syncthreads();

    // ---- 5. gates + h update; thread -> (batch ub, cols uk..uk+3) ----
    {
      float hyv[4];
      unsigned short hx[4];
      #pragma unroll
      for (int c2 = 0; c2 < 4; ++c2) {
        const int kk = uk + c2;
        float pr = hp[kk * 33 + ub]        + (&bhr.x)[c2] + (&ipr.x)[c2];
        float pz = hp[(32 + kk) * 33 + ub] + (&bhz.x)[c2] + (&ipz.x)[c2];
        float pn = hp[(64 + kk) * 33 + ub] + (&bhn.x)[c2];
        float rr = sigmoid_f(pr);
        float zz = sigmoid_f(pz);
        float nn = tanh_f((&ipn.x)[c2] + rr * pn);
        float h0 = hf[ub * 32 + kk];
        float hy = (1.f - zz) * nn + zz * h0;
        hf[ub * 32 + kk] = hy;
        hyv[c2] = hy;
        hx[c2] = __builtin_bit_cast(unsigned short, (_Float16)hy);
      }
      // publish first (gets to LLC earliest), then y
      unsigned long long hw =
          (unsigned long long)hx[0] | ((unsigned long long)hx[1] << 16) |
          ((unsigned long long)hx[2] << 32) | ((unsigned long long)hx[3] << 48);
      __hip_atomic_store(hbuf + ((size_t)((t + 1) & 1)) * 4096 + ub * 128 + (colg >> 2),
                         hw, __ATOMIC_RELAXED, __HIP_MEMORY_SCOPE_AGENT);
      float4 yo = { hyv[0], hyv[1], hyv[2], hyv[3] };
      *(float4*)(y + iprow * HID + colg) = yo;
      if (hlast && t == S_LEN - 1)
        *(float4*)(hlast + (size_t)ub * HID + colg) = yo;
    }

    // ---- 6. drain stores, align waves, signal ----
    asm volatile("s_waitcnt vmcnt(0)" ::: "memory");
    __syncthreads();
    if (tid == 0)
      __hip_atomic_store(fl + (size_t)t * NWG + p, 1u,
                         __ATOMIC_RELAXED, __HIP_MEMORY_SCOPE_AGENT);
  }
}

// ---------------------------------------------------------------------------
// ws layout (bytes)
// ---------------------------------------------------------------------------
#define BF0_OFF 0ull
#define BF1_OFF 1572864ull
#define WI0_OFF 3145728ull
#define WI1_OFF 4718592ull
#define HB_OFF  6291456ull        // 65536 B (f16 h double buffer)
#define FL0_OFF 6356992ull        // 131072 B ([2048][16] dwords)
#define FL1_OFF 6488064ull        // 131072 B
#define IP_OFF  8388608ull

template <typename IPT>
static void run_all(const float* x,
                    const float* Wi0, const float* bi0, const float* Wh0, const float* bh0,
                    const float* Wi1, const float* bi1, const float* Wh1, const float* bh1,
                    float* out, char* ws, hipStream_t stream) {
  unsigned int* bf0  = (unsigned int*)(ws + BF0_OFF);
  unsigned int* bf1  = (unsigned int*)(ws + BF1_OFF);
  __bf16* wi0b = (__bf16*)(ws + WI0_OFF);
  __bf16* wi1b = (__bf16*)(ws + WI1_OFF);
  unsigned long long* hbuf = (unsigned long long*)(ws + HB_OFF);
  unsigned int* fl0  = (unsigned int*)(ws + FL0_OFF);
  unsigned int* fl1  = (unsigned int*)(ws + FL1_OFF);
  IPT* ip = (IPT*)(ws + IP_OFF);
  float* y0    = out;
  float* hlast = out + (size_t)MROWS * HID;

  // zero h double-buffer + both layers' flags (graph-replay determinism)
  hipMemsetAsync(ws + HB_OFF, 0, 65536 + 131072 + 131072, stream);

  prep_bfrag<<<dim3(1536), dim3(256), 0, stream>>>(Wh0, bf0);
  prep_bfrag<<<dim3(1536), dim3(256), 0, stream>>>(Wh1, bf1);
  prep_wib<<<dim3(3072), dim3(256), 0, stream>>>(Wi0, wi0b);
  prep_wib<<<dim3(3072), dim3(256), 0, stream>>>(Wi1, wi1b);

  gemm_ip<IPT><<<dim3(24, 1024), dim3(256), 0, stream>>>(x, wi0b, bi0, ip);
  gru_rec3<IPT><<<dim3(NWG), dim3(256), 0, stream>>>(ip, (const uint4*)bf0, bh0,
                                                     y0, (float*)nullptr, hbuf, fl0);
  hipMemsetAsync(ws + HB_OFF, 0, 65536, stream);   // re-zero h for layer 1
  gemm_ip<IPT><<<dim3(24, 1024), dim3(256), 0, stream>>>(y0, wi1b, bi1, ip);
  gru_rec3<IPT><<<dim3(NWG), dim3(256), 0, stream>>>(ip, (const uint4*)bf1, bh1,
                                                     out, hlast, hbuf, fl1);
}

extern "C" void kernel_launch(void* const* d_in, const int* in_sizes, int n_in,
                              void* d_out, int out_size, void* d_ws, size_t ws_size,
                              hipStream_t stream) {
  const float* x   = (const float*)d_in[0];
  const float* Wi0 = (const float*)d_in[1];
  const float* bi0 = (const float*)d_in[2];
  const float* Wh0 = (const float*)d_in[3];
  const float* bh0 = (const float*)d_in[4];
  const float* Wi1 = (const float*)d_in[5];
  const float* bi1 = (const float*)d_in[6];
  const float* Wh1 = (const float*)d_in[7];
  const float* bh1 = (const float*)d_in[8];
  float* out = (float*)d_out;
  char*  ws  = (char*)d_ws;

  const size_t need_f32 = IP_OFF + (size_t)MROWS * G3 * 4;
  if (ws_size >= need_f32) {
    run_all<float>(x, Wi0, bi0, Wh0, bh0, Wi1, bi1, Wh1, bh1, out, ws, stream);
  } else {
    run_all<unsigned short>(x, Wi0, bi0, Wh0, bh0, Wi1, bi1, Wh1, bh1, out, ws, stream);
  }
}

// Round 5
// 14668.425 us; speedup vs baseline: 3.2669x; 1.3133x over previous
//
#include <hip/hip_runtime.h>
#include <hip/hip_bf16.h>

// ---------------------------------------------------------------------------
// GRU, 2 layers, B=32, S=2048, D=H=512.
//   gemm:   ip0 = x @ Wi0^T + bi0   (bf16 MFMA)                [verified]
//   fused:  32 WGs. WG 0..15 = layer-0 rec (16-way col-split, Wh0 in VGPRs,
//           f16 h over LLC + flags). WG 16..31 = layer-1 rec, consuming
//           y0h[t] (== h0 publish) as it is produced: ip1 computed in-kernel
//           (Wi1 B-frags LDS-resident), Wh1 in VGPRs. L1 trails L0 by ~1 step
//           => layer-1 time is hidden. No ip1 array, no second GEMM.
//   r5 fix: layer-1 LDS ipn pointer aliased hf (98304+16896 == hf offset),
//           corrupting h1 state every step. ipn now at 98304+12672.
// ---------------------------------------------------------------------------

typedef __bf16    bf16x8 __attribute__((ext_vector_type(8)));
typedef __bf16    bf16x4 __attribute__((ext_vector_type(4)));
typedef float     f32x4  __attribute__((ext_vector_type(4)));
typedef _Float16  f16x2  __attribute__((ext_vector_type(2)));
typedef _Float16  f16x8  __attribute__((ext_vector_type(8)));

#define S_LEN 2048
#define BATCH 32
#define HID   512
#define G3    1536
#define MROWS (BATCH * S_LEN)
#define NWG   16

__device__ inline float sigmoid_f(float x) { return 1.f / (1.f + __expf(-x)); }
__device__ inline float tanh_f(float x) {
  float e = __expf(2.f * x);
  return 1.f - 2.f / (e + 1.f);
}

template <typename IPT>
__device__ inline void store_ip(IPT* p, float v) {
  if constexpr (sizeof(IPT) == 4) *p = v;
  else *p = __builtin_bit_cast(unsigned short, (__bf16)v);
}
template <typename IPT>
__device__ inline float4 load_ip4(const IPT* p) {
  if constexpr (sizeof(IPT) == 4) {
    return *(const float4*)p;
  } else {
    ushort4 u = *(const ushort4*)p;
    float4 r;
    r.x = __uint_as_float((unsigned)u.x << 16);
    r.y = __uint_as_float((unsigned)u.y << 16);
    r.z = __uint_as_float((unsigned)u.z << 16);
    r.w = __uint_as_float((unsigned)u.w << 16);
    return r;
  }
}

// ---------------------------------------------------------------------------
// prep: Wi0 fp32 -> bf16 (for ip GEMM)
// ---------------------------------------------------------------------------
__global__ void prep_wib(const float* __restrict__ W, __bf16* __restrict__ o) {
  int i = blockIdx.x * 256 + threadIdx.x;
  o[i] = (__bf16)W[i];
}

// ---------------------------------------------------------------------------
// prep: (1536,512) fp32 weight -> per-WG B-fragment order (f16 pairs).
//   idx = p*24576 + set*12288 + frag*256 + lane*4 + d
//   frag = nt*16 + ks ; j = set*48 + nt*16 + (lane&15) in [0,96)
//   gate g = j>>5, klocal = j&31 -> row = g*512 + p*32 + klocal
//   k = ks*32 + 8*(lane>>4) + 2*d
// Used for Wh0, Wh1 (VGPR-resident) and Wi1 (LDS-resident).
// ---------------------------------------------------------------------------
__global__ void prep_bfrag(const float* __restrict__ W, unsigned int* __restrict__ out) {
  int idx = blockIdx.x * 256 + threadIdx.x;   // grid = 393216/256 = 1536
  int p    = idx / 24576;
  int r    = idx % 24576;
  int set  = r / 12288;
  int r2   = r % 12288;
  int frag = r2 / 256;
  int lq   = r2 % 256;
  int l    = lq >> 2, d = lq & 3;
  int nt   = frag >> 4, ks = frag & 15;
  int j    = set * 48 + nt * 16 + (l & 15);
  int g    = j >> 5, kl = j & 31;
  int row  = g * 512 + p * 32 + kl;
  int k    = ks * 32 + 8 * (l >> 4) + 2 * d;
  f16x2 pk = { (_Float16)W[(size_t)row * HID + k],
               (_Float16)W[(size_t)row * HID + k + 1] };
  out[idx] = __builtin_bit_cast(unsigned int, pk);
}

// ---------------------------------------------------------------------------
// ip GEMM (verified): C(M,1536)=A(M,512)@Bw(1536,512)^T + bias
// ---------------------------------------------------------------------------
template <typename IPT>
__global__ __launch_bounds__(256) void gemm_ip(
    const float* __restrict__ A, const __bf16* __restrict__ Bw,
    const float* __restrict__ bias, IPT* __restrict__ C) {
  constexpr int K = 512;
  __shared__ __align__(16) __bf16 As[64][72];
  __shared__ __align__(16) __bf16 Bs[64][72];
  const int tid  = threadIdx.x;
  const int bm   = blockIdx.y, bn = blockIdx.x;
  const int lane = tid & 63,  wave = tid >> 6;
  const int wr   = wave >> 1, wc   = wave & 1;
  f32x4 acc[2][2] = {};
  const int r = tid >> 2, q = tid & 3;
  const float*  Arow = A  + (size_t)(bm * 64 + r) * K;
  const __bf16* Brow = Bw + (size_t)(bn * 64 + r) * K;

  for (int k0 = 0; k0 < K; k0 += 64) {
    const float4* as = (const float4*)(Arow + k0);
    #pragma unroll
    for (int i = 0; i < 4; ++i) {
      float4 v = as[q + 4 * i];
      bf16x4 pkt = { (__bf16)v.x, (__bf16)v.y, (__bf16)v.z, (__bf16)v.w };
      *(bf16x4*)&As[r][4 * (q + 4 * i)] = pkt;
    }
    const uint4* bs = (const uint4*)(Brow + k0);
    uint4* bd = (uint4*)&Bs[r][0];
    bd[q]     = bs[q];
    bd[q + 4] = bs[q + 4];
    __syncthreads();

    #pragma unroll
    for (int kk = 0; kk < 64; kk += 32) {
      const int kb = kk + 8 * (lane >> 4);
      bf16x8 a0 = *(const bf16x8*)&As[wr * 32 +      (lane & 15)][kb];
      bf16x8 a1 = *(const bf16x8*)&As[wr * 32 + 16 + (lane & 15)][kb];
      bf16x8 b0 = *(const bf16x8*)&Bs[wc * 32 +      (lane & 15)][kb];
      bf16x8 b1 = *(const bf16x8*)&Bs[wc * 32 + 16 + (lane & 15)][kb];
      acc[0][0] = __builtin_amdgcn_mfma_f32_16x16x32_bf16(a0, b0, acc[0][0], 0, 0, 0);
      acc[0][1] = __builtin_amdgcn_mfma_f32_16x16x32_bf16(a0, b1, acc[0][1], 0, 0, 0);
      acc[1][0] = __builtin_amdgcn_mfma_f32_16x16x32_bf16(a1, b0, acc[1][0], 0, 0, 0);
      acc[1][1] = __builtin_amdgcn_mfma_f32_16x16x32_bf16(a1, b1, acc[1][1], 0, 0, 0);
    }
    __syncthreads();
  }

  const int row0 = bm * 64 + wr * 32 + (lane >> 4) * 4;
  const int col0 = bn * 64 + wc * 32 + (lane & 15);
  #pragma unroll
  for (int fm = 0; fm < 2; ++fm)
    #pragma unroll
    for (int fn = 0; fn < 2; ++fn) {
      int n = col0 + fn * 16;
      float bv = bias[n];
      #pragma unroll
      for (int reg = 0; reg < 4; ++reg) {
        size_t off = (size_t)(row0 + fm * 16 + reg) * G3 + n;
        store_ip<IPT>(C + off, acc[fm][fn][reg] + bv);
      }
    }
}

// ---------------------------------------------------------------------------
// fused recurrence: WG 0..15 layer 0, WG 16..31 layer 1.
// ---------------------------------------------------------------------------
template <typename IPT>
__global__ __launch_bounds__(256, 1) void gru_fused(
    const IPT* __restrict__ ip0,                 // (B*S, 1536) layer-0 input proj
    const uint4* __restrict__ bfWh0,
    const float* __restrict__ bh0,
    const uint4* __restrict__ bfWh1,
    const uint4* __restrict__ bfWi1,
    const float* __restrict__ bi1,
    const float* __restrict__ bh1,
    float* __restrict__ y1,                      // (B*S, 512) -> d_out
    float* __restrict__ hlast,                   // (B, 512)   -> d_out tail
    unsigned long long* __restrict__ h0buf,      // [2][32][128] 8B
    unsigned long long* __restrict__ h1buf,      // [2][32][128] 8B
    unsigned long long* __restrict__ y0h,        // [S][32][128] 8B (f16 y0)
    unsigned int* __restrict__ fl0,              // [S][16]
    unsigned int* __restrict__ fl1) {            // [S][16]
  __shared__ __align__(16) char smem[119296];
  const int bid = blockIdx.x, tid = threadIdx.x;
  const int lane = tid & 63, wave = tid >> 6;
  const int set = wave & 1, m = wave >> 1;
  const int ub = tid >> 3, uk = (tid & 7) * 4;
  const int arow  = m * 16 + (lane & 15);
  const int abyte = arow * 1024 + 16 * (lane >> 4);

  if (bid < NWG) {
    // ======================= layer 0 =======================
    const int p = bid;
    const int colg = p * 32 + uk;
    float* hp = (float*)smem;              // [96*33]
    float* hf = (float*)(smem + 12672);    // [1024]

    uint4 wf[48];
    {
      const uint4* bsrc = bfWh0 + ((size_t)(p * 2 + set) * 48) * 64 + lane;
      #pragma unroll
      for (int i = 0; i < 48; ++i) wf[i] = bsrc[i * 64];
    }
    const float4 bhr = *(const float4*)(bh0 + colg);
    const float4 bhz = *(const float4*)(bh0 + 512 + colg);
    const float4 bhn = *(const float4*)(bh0 + 1024 + colg);
    for (int i = tid; i < 1024; i += 256) hf[i] = 0.f;
    __syncthreads();

    for (int t = 0; t < S_LEN; ++t) {
      const size_t iprow = (size_t)ub * S_LEN + t;
      float4 ipr = load_ip4<IPT>(ip0 + iprow * G3 + colg);
      float4 ipz = load_ip4<IPT>(ip0 + iprow * G3 + 512 + colg);
      float4 ipn = load_ip4<IPT>(ip0 + iprow * G3 + 1024 + colg);
      __builtin_amdgcn_sched_barrier(0);

      if (t > 0) {
        const unsigned int* f = fl0 + (size_t)(t - 1) * NWG;
        while (true) {
          unsigned v = (lane < NWG)
              ? __hip_atomic_load(f + lane, __ATOMIC_RELAXED, __HIP_MEMORY_SCOPE_AGENT)
              : 1u;
          if (__all(v != 0)) break;
          __builtin_amdgcn_s_sleep(1);
        }
      }
      __builtin_amdgcn_sched_barrier(0);

      const char* hb = (const char*)h0buf + (t & 1) * 32768 + abyte;
      uint4 af[16];
      #pragma unroll
      for (int ks = 0; ks < 16; ++ks)
        asm volatile("global_load_dwordx4 %0, %1, off offset:%2 sc0 sc1"
                     : "=v"(af[ks]) : "v"(hb), "i"(ks * 64) : "memory");
      asm volatile("s_waitcnt vmcnt(0)" ::: "memory");
      __builtin_amdgcn_sched_barrier(0);

      f32x4 acc0 = {}, acc1 = {}, acc2 = {};
      #pragma unroll
      for (int ks = 0; ks < 16; ++ks) {
        f16x8 a = __builtin_bit_cast(f16x8, af[ks]);
        acc0 = __builtin_amdgcn_mfma_f32_16x16x32_f16(a, __builtin_bit_cast(f16x8, wf[ks]),      acc0, 0, 0, 0);
        acc1 = __builtin_amdgcn_mfma_f32_16x16x32_f16(a, __builtin_bit_cast(f16x8, wf[16 + ks]), acc1, 0, 0, 0);
        acc2 = __builtin_amdgcn_mfma_f32_16x16x32_f16(a, __builtin_bit_cast(f16x8, wf[32 + ks]), acc2, 0, 0, 0);
      }
      {
        const int j0 = set * 48 + (lane & 15);
        const int bt = m * 16 + (lane >> 4) * 4;
        #pragma unroll
        for (int q = 0; q < 4; ++q) {
          hp[(j0 +  0) * 33 + bt + q] = acc0[q];
          hp[(j0 + 16) * 33 + bt + q] = acc1[q];
          hp[(j0 + 32) * 33 + bt + q] = acc2[q];
        }
      }
      __syncthreads();

      unsigned short hx[4];
      #pragma unroll
      for (int c2 = 0; c2 < 4; ++c2) {
        const int kk = uk + c2;
        float pr = hp[kk * 33 + ub]        + (&bhr.x)[c2] + (&ipr.x)[c2];
        float pz = hp[(32 + kk) * 33 + ub] + (&bhz.x)[c2] + (&ipz.x)[c2];
        float pn = hp[(64 + kk) * 33 + ub] + (&bhn.x)[c2];
        float rr = sigmoid_f(pr);
        float zz = sigmoid_f(pz);
        float nn = tanh_f((&ipn.x)[c2] + rr * pn);
        float h0v = hf[ub * 32 + kk];
        float hy = (1.f - zz) * nn + zz * h0v;
        hf[ub * 32 + kk] = hy;
        hx[c2] = __builtin_bit_cast(unsigned short, (_Float16)hy);
      }
      const unsigned long long hw =
          (unsigned long long)hx[0] | ((unsigned long long)hx[1] << 16) |
          ((unsigned long long)hx[2] << 32) | ((unsigned long long)hx[3] << 48);
      const size_t slot = (size_t)ub * 128 + (colg >> 2);
      __hip_atomic_store(h0buf + ((size_t)((t + 1) & 1)) * 4096 + slot, hw,
                         __ATOMIC_RELAXED, __HIP_MEMORY_SCOPE_AGENT);
      __hip_atomic_store(y0h + (size_t)t * 4096 + slot, hw,
                         __ATOMIC_RELAXED, __HIP_MEMORY_SCOPE_AGENT);
      asm volatile("s_waitcnt vmcnt(0)" ::: "memory");
      __syncthreads();
      if (tid == 0)
        __hip_atomic_store(fl0 + (size_t)t * NWG + p, 1u,
                           __ATOMIC_RELAXED, __HIP_MEMORY_SCOPE_AGENT);
    }
  } else {
    // ======================= layer 1 =======================
    const int p = bid - NWG;
    const int colg = p * 32 + uk;
    uint4* wiB  = (uint4*)smem;                     // [6144] = 96 KB
    float* comb = (float*)(smem + 98304);           // [64*33] r,z (ip+hp)
    float* hpn  = (float*)(smem + 106752);          // [32*33] n (hp part)
    float* ipn  = (float*)(smem + 110976);          // [32*33] n (ip part)
    float* hf   = (float*)(smem + 115200);          // [1024]

    uint4 wf[48];
    {
      const uint4* bsrc = bfWh1 + ((size_t)(p * 2 + set) * 48) * 64 + lane;
      #pragma unroll
      for (int i = 0; i < 48; ++i) wf[i] = bsrc[i * 64];
    }
    {
      const uint4* src = bfWi1 + (size_t)p * 6144;
      for (int i = tid; i < 6144; i += 256) wiB[i] = src[i];
    }
    const float4 bir = *(const float4*)(bi1 + colg);
    const float4 biz = *(const float4*)(bi1 + 512 + colg);
    const float4 bin = *(const float4*)(bi1 + 1024 + colg);
    const float4 bhr = *(const float4*)(bh1 + colg);
    const float4 bhz = *(const float4*)(bh1 + 512 + colg);
    const float4 bhn = *(const float4*)(bh1 + 1024 + colg);
    for (int i = tid; i < 1024; i += 256) hf[i] = 0.f;
    __syncthreads();

    for (int t = 0; t < S_LEN; ++t) {
      // -- wait for layer-0 row t --
      {
        const unsigned int* f = fl0 + (size_t)t * NWG;
        while (true) {
          unsigned v = (lane < NWG)
              ? __hip_atomic_load(f + lane, __ATOMIC_RELAXED, __HIP_MEMORY_SCOPE_AGENT)
              : 1u;
          if (__all(v != 0)) break;
          __builtin_amdgcn_s_sleep(1);
        }
      }
      __builtin_amdgcn_sched_barrier(0);

      // -- load y0 row t as A-frags --
      uint4 ay[16];
      {
        const char* yb = (const char*)y0h + (size_t)t * 32768 + abyte;
        #pragma unroll
        for (int ks = 0; ks < 16; ++ks)
          asm volatile("global_load_dwordx4 %0, %1, off offset:%2 sc0 sc1"
                       : "=v"(ay[ks]) : "v"(yb), "i"(ks * 64) : "memory");
        asm volatile("s_waitcnt vmcnt(0)" ::: "memory");
      }
      __builtin_amdgcn_sched_barrier(0);

      // -- ip1 = y0 @ Wi1^T (B from LDS) --
      f32x4 ai0 = {}, ai1 = {}, ai2 = {};
      {
        const int wb = set * 3072 + lane;
        #pragma unroll
        for (int ks = 0; ks < 16; ++ks) {
          f16x8 a = __builtin_bit_cast(f16x8, ay[ks]);
          ai0 = __builtin_amdgcn_mfma_f32_16x16x32_f16(a, __builtin_bit_cast(f16x8, wiB[wb + ks * 64]),        ai0, 0, 0, 0);
          ai1 = __builtin_amdgcn_mfma_f32_16x16x32_f16(a, __builtin_bit_cast(f16x8, wiB[wb + (16 + ks) * 64]), ai1, 0, 0, 0);
          ai2 = __builtin_amdgcn_mfma_f32_16x16x32_f16(a, __builtin_bit_cast(f16x8, wiB[wb + (32 + ks) * 64]), ai2, 0, 0, 0);
        }
      }

      // -- wait own h1(t-1) --
      if (t > 0) {
        const unsigned int* f = fl1 + (size_t)(t - 1) * NWG;
        while (true) {
          unsigned v = (lane < NWG)
              ? __hip_atomic_load(f + lane, __ATOMIC_RELAXED, __HIP_MEMORY_SCOPE_AGENT)
              : 1u;
          if (__all(v != 0)) break;
          __builtin_amdgcn_s_sleep(1);
        }
      }
      __builtin_amdgcn_sched_barrier(0);

      uint4 ah[16];
      {
        const char* hb = (const char*)h1buf + (t & 1) * 32768 + abyte;
        #pragma unroll
        for (int ks = 0; ks < 16; ++ks)
          asm volatile("global_load_dwordx4 %0, %1, off offset:%2 sc0 sc1"
                       : "=v"(ah[ks]) : "v"(hb), "i"(ks * 64) : "memory");
        asm volatile("s_waitcnt vmcnt(0)" ::: "memory");
      }
      __builtin_amdgcn_sched_barrier(0);

      f32x4 ac0 = {}, ac1 = {}, ac2 = {};
      #pragma unroll
      for (int ks = 0; ks < 16; ++ks) {
        f16x8 a = __builtin_bit_cast(f16x8, ah[ks]);
        ac0 = __builtin_amdgcn_mfma_f32_16x16x32_f16(a, __builtin_bit_cast(f16x8, wf[ks]),      ac0, 0, 0, 0);
        ac1 = __builtin_amdgcn_mfma_f32_16x16x32_f16(a, __builtin_bit_cast(f16x8, wf[16 + ks]), ac1, 0, 0, 0);
        ac2 = __builtin_amdgcn_mfma_f32_16x16x32_f16(a, __builtin_bit_cast(f16x8, wf[32 + ks]), ac2, 0, 0, 0);
      }

      // -- scatter: r,z combined; n split (ip vs hp) --
      {
        const int j0 = set * 48 + (lane & 15);
        const int bt = m * 16 + (lane >> 4) * 4;
        if (set == 0) {
          #pragma unroll
          for (int q = 0; q < 4; ++q) {
            comb[(j0 +  0) * 33 + bt + q] = ai0[q] + ac0[q];
            comb[(j0 + 16) * 33 + bt + q] = ai1[q] + ac1[q];
            comb[(j0 + 32) * 33 + bt + q] = ai2[q] + ac2[q];
          }
        } else {
          #pragma unroll
          for (int q = 0; q < 4; ++q) {
            comb[j0 * 33 + bt + q] = ai0[q] + ac0[q];          // j 48..63 (z hi)
            hpn[(j0 - 48) * 33 + bt + q] = ac1[q];             // j 64..79
            ipn[(j0 - 48) * 33 + bt + q] = ai1[q];
            hpn[(j0 - 32) * 33 + bt + q] = ac2[q];             // j 80..95
            ipn[(j0 - 32) * 33 + bt + q] = ai2[q];
          }
        }
      }
      __syncthreads();

      float hyv[4];
      unsigned short hx[4];
      #pragma unroll
      for (int c2 = 0; c2 < 4; ++c2) {
        const int kk = uk + c2;
        float sr = comb[kk * 33 + ub]        + (&bir.x)[c2] + (&bhr.x)[c2];
        float sz = comb[(32 + kk) * 33 + ub] + (&biz.x)[c2] + (&bhz.x)[c2];
        float vi = ipn[kk * 33 + ub] + (&bin.x)[c2];
        float vh = hpn[kk * 33 + ub] + (&bhn.x)[c2];
        float rr = sigmoid_f(sr);
        float zz = sigmoid_f(sz);
        float nn = tanh_f(vi + rr * vh);
        float h0v = hf[ub * 32 + kk];
        float hy = (1.f - zz) * nn + zz * h0v;
        hf[ub * 32 + kk] = hy;
        hyv[c2] = hy;
        hx[c2] = __builtin_bit_cast(unsigned short, (_Float16)hy);
      }
      const unsigned long long hw =
          (unsigned long long)hx[0] | ((unsigned long long)hx[1] << 16) |
          ((unsigned long long)hx[2] << 32) | ((unsigned long long)hx[3] << 48);
      __hip_atomic_store(h1buf + ((size_t)((t + 1) & 1)) * 4096 + ub * 128 + (colg >> 2),
                         hw, __ATOMIC_RELAXED, __HIP_MEMORY_SCOPE_AGENT);
      asm volatile("s_waitcnt vmcnt(0)" ::: "memory");
      __syncthreads();
      if (tid == 0)
        __hip_atomic_store(fl1 + (size_t)t * NWG + p, 1u,
                           __ATOMIC_RELAXED, __HIP_MEMORY_SCOPE_AGENT);

      // -- y1 fp32 store, off the critical path --
      float4 yo = { hyv[0], hyv[1], hyv[2], hyv[3] };
      *(float4*)(y1 + ((size_t)ub * S_LEN + t) * HID + colg) = yo;
      if (t == S_LEN - 1)
        *(float4*)(hlast + (size_t)ub * HID + colg) = yo;
    }
  }
}

// ---------------------------------------------------------------------------
// ws layout (bytes)
// ---------------------------------------------------------------------------
#define BFWH0_OFF 0ull
#define BFWH1_OFF 1572864ull
#define BFWI1_OFF 3145728ull
#define WI0_OFF   4718592ull
#define H0_OFF    6291456ull      // 65536
#define H1_OFF    6356992ull      // 65536
#define FL0_OFF   6422528ull      // 131072
#define FL1_OFF   6553600ull      // 131072
#define Y0H_OFF   6684672ull      // 67108864
#define IP_OFF    73793536ull

template <typename IPT>
static void run_all(const float* x,
                    const float* Wi0, const float* bi0, const float* Wh0, const float* bh0,
                    const float* Wi1, const float* bi1, const float* Wh1, const float* bh1,
                    float* out, char* ws, hipStream_t stream) {
  unsigned int* bfWh0 = (unsigned int*)(ws + BFWH0_OFF);
  unsigned int* bfWh1 = (unsigned int*)(ws + BFWH1_OFF);
  unsigned int* bfWi1 = (unsigned int*)(ws + BFWI1_OFF);
  __bf16* wi0b = (__bf16*)(ws + WI0_OFF);
  unsigned long long* h0buf = (unsigned long long*)(ws + H0_OFF);
  unsigned long long* h1buf = (unsigned long long*)(ws + H1_OFF);
  unsigned int* fl0 = (unsigned int*)(ws + FL0_OFF);
  unsigned int* fl1 = (unsigned int*)(ws + FL1_OFF);
  unsigned long long* y0h = (unsigned long long*)(ws + Y0H_OFF);
  IPT* ip = (IPT*)(ws + IP_OFF);
  float* y1    = out;
  float* hlast = out + (size_t)MROWS * HID;

  // zero h bufs + both flag arrays (contiguous region) each launch
  hipMemsetAsync(ws + H0_OFF, 0, 65536 + 65536 + 131072 + 131072, stream);

  prep_bfrag<<<dim3(1536), dim3(256), 0, stream>>>(Wh0, bfWh0);
  prep_bfrag<<<dim3(1536), dim3(256), 0, stream>>>(Wh1, bfWh1);
  prep_bfrag<<<dim3(1536), dim3(256), 0, stream>>>(Wi1, bfWi1);
  prep_wib<<<dim3(3072), dim3(256), 0, stream>>>(Wi0, wi0b);

  gemm_ip<IPT><<<dim3(24, 1024), dim3(256), 0, stream>>>(x, wi0b, bi0, ip);
  gru_fused<IPT><<<dim3(2 * NWG), dim3(256), 0, stream>>>(
      ip, (const uint4*)bfWh0, bh0, (const uint4*)bfWh1, (const uint4*)bfWi1,
      bi1, bh1, y1, hlast, h0buf, h1buf, y0h, fl0, fl1);
}

extern "C" void kernel_launch(void* const* d_in, const int* in_sizes, int n_in,
                              void* d_out, int out_size, void* d_ws, size_t ws_size,
                              hipStream_t stream) {
  const float* x   = (const float*)d_in[0];
  const float* Wi0 = (const float*)d_in[1];
  const float* bi0 = (const float*)d_in[2];
  const float* Wh0 = (const float*)d_in[3];
  const float* bh0 = (const float*)d_in[4];
  const float* Wi1 = (const float*)d_in[5];
  const float* bi1 = (const float*)d_in[6];
  const float* Wh1 = (const float*)d_in[7];
  const float* bh1 = (const float*)d_in[8];
  float* out = (float*)d_out;
  char*  ws  = (char*)d_ws;

  const size_t need_f32 = IP_OFF + (size_t)MROWS * G3 * 4;
  if (ws_size >= need_f32) {
    run_all<float>(x, Wi0, bi0, Wh0, bh0, Wi1, bi1, Wh1, bh1, out, ws, stream);
  } else {
    run_all<unsigned short>(x, Wi0, bi0, Wh0, bh0, Wi1, bi1, Wh1, bh1, out, ws, stream);
  }
}

// Round 7
// 13663.043 us; speedup vs baseline: 3.5073x; 1.0736x over previous
//
#include <hip/hip_runtime.h>
#include <hip/hip_bf16.h>

// ---------------------------------------------------------------------------
// GRU, 2 layers, B=32, S=2048, D=H=512.
//   gemm:   ip0 = x @ Wi0^T + bi0   (bf16 MFMA)                [verified]
//   fused:  32 WGs. WG 0..15 = layer-0 rec, WG 16..31 = layer-1 rec.
//   r7: operand-swapped MFMA  hp^T = W(96x512) @ H^T(512x32):
//       A-frag = weights (VGPR/LDS resident), B-frag = h. D: row=cols (4/lane),
//       col=batch (1/lane) -> gates in-register, publish = ONE 8B atomic store
//       (4 consecutive f16 cols). Sync protocol is verbatim r5 (per-WG flags,
//       vmcnt(0)+__syncthreads+tid0 signal, asm dwordx4 sc0 sc1 loads).
// ---------------------------------------------------------------------------

typedef __bf16    bf16x8 __attribute__((ext_vector_type(8)));
typedef __bf16    bf16x4 __attribute__((ext_vector_type(4)));
typedef float     f32x4  __attribute__((ext_vector_type(4)));
typedef _Float16  f16x2  __attribute__((ext_vector_type(2)));
typedef _Float16  f16x8  __attribute__((ext_vector_type(8)));

#define S_LEN 2048
#define BATCH 32
#define HID   512
#define G3    1536
#define MROWS (BATCH * S_LEN)
#define NWG   16

__device__ inline float sigmoid_f(float x) { return 1.f / (1.f + __expf(-x)); }
__device__ inline float tanh_f(float x) {
  float e = __expf(2.f * x);
  return 1.f - 2.f / (e + 1.f);
}

template <typename IPT>
__device__ inline void store_ip(IPT* p, float v) {
  if constexpr (sizeof(IPT) == 4) *p = v;
  else *p = __builtin_bit_cast(unsigned short, (__bf16)v);
}
template <typename IPT>
__device__ inline float4 load_ip4(const IPT* p) {
  if constexpr (sizeof(IPT) == 4) {
    return *(const float4*)p;
  } else {
    ushort4 u = *(const ushort4*)p;
    float4 r;
    r.x = __uint_as_float((unsigned)u.x << 16);
    r.y = __uint_as_float((unsigned)u.y << 16);
    r.z = __uint_as_float((unsigned)u.z << 16);
    r.w = __uint_as_float((unsigned)u.w << 16);
    return r;
  }
}

// ---------------------------------------------------------------------------
// prep: Wi0 fp32 -> bf16 (for ip GEMM)
// ---------------------------------------------------------------------------
__global__ void prep_wib(const float* __restrict__ W, __bf16* __restrict__ o) {
  int i = blockIdx.x * 256 + threadIdx.x;
  o[i] = (__bf16)W[i];
}

// ---------------------------------------------------------------------------
// prep: (1536,512) fp32 weight -> A-fragment order (f16 pairs), operand-swap.
// A-frag (16x16x32): lane l holds A[row][k], row = l&15, k = ks*32+(l>>4)*8+e.
// Tile (p, mh, g): A rows = g*512 + p*32 + mh*16 + (l&15).
//   dword idx = ((p*2+mh)*48 + g*16 + ks)*256 + l*4 + d ; k = ks*32+(l>>4)*8+2d
// Used for Wh0, Wh1 (VGPR-resident) and Wi1 (LDS-resident).
// ---------------------------------------------------------------------------
__global__ void prep_bfrag(const float* __restrict__ W, unsigned int* __restrict__ out) {
  int idx = blockIdx.x * 256 + threadIdx.x;   // grid = 393216/256 = 1536
  int p    = idx / 24576;
  int r    = idx % 24576;
  int mh   = r / 12288;
  int r2   = r % 12288;
  int frag = r2 / 256;                        // g*16 + ks
  int lq   = r2 % 256;
  int l    = lq >> 2, d = lq & 3;
  int g    = frag >> 4, ks = frag & 15;
  int row  = g * 512 + p * 32 + mh * 16 + (l & 15);
  int k    = ks * 32 + (l >> 4) * 8 + 2 * d;
  f16x2 pk = { (_Float16)W[(size_t)row * HID + k],
               (_Float16)W[(size_t)row * HID + k + 1] };
  out[idx] = __builtin_bit_cast(unsigned int, pk);
}

// ---------------------------------------------------------------------------
// ip GEMM (verified): C(M,1536)=A(M,512)@Bw(1536,512)^T + bias
// ---------------------------------------------------------------------------
template <typename IPT>
__global__ __launch_bounds__(256) void gemm_ip(
    const float* __restrict__ A, const __bf16* __restrict__ Bw,
    const float* __restrict__ bias, IPT* __restrict__ C) {
  constexpr int K = 512;
  __shared__ __align__(16) __bf16 As[64][72];
  __shared__ __align__(16) __bf16 Bs[64][72];
  const int tid  = threadIdx.x;
  const int bm   = blockIdx.y, bn = blockIdx.x;
  const int lane = tid & 63,  wave = tid >> 6;
  const int wr   = wave >> 1, wc   = wave & 1;
  f32x4 acc[2][2] = {};
  const int r = tid >> 2, q = tid & 3;
  const float*  Arow = A  + (size_t)(bm * 64 + r) * K;
  const __bf16* Brow = Bw + (size_t)(bn * 64 + r) * K;

  for (int k0 = 0; k0 < K; k0 += 64) {
    const float4* as = (const float4*)(Arow + k0);
    #pragma unroll
    for (int i = 0; i < 4; ++i) {
      float4 v = as[q + 4 * i];
      bf16x4 pkt = { (__bf16)v.x, (__bf16)v.y, (__bf16)v.z, (__bf16)v.w };
      *(bf16x4*)&As[r][4 * (q + 4 * i)] = pkt;
    }
    const uint4* bs = (const uint4*)(Brow + k0);
    uint4* bd = (uint4*)&Bs[r][0];
    bd[q]     = bs[q];
    bd[q + 4] = bs[q + 4];
    __syncthreads();

    #pragma unroll
    for (int kk = 0; kk < 64; kk += 32) {
      const int kb = kk + 8 * (lane >> 4);
      bf16x8 a0 = *(const bf16x8*)&As[wr * 32 +      (lane & 15)][kb];
      bf16x8 a1 = *(const bf16x8*)&As[wr * 32 + 16 + (lane & 15)][kb];
      bf16x8 b0 = *(const bf16x8*)&Bs[wc * 32 +      (lane & 15)][kb];
      bf16x8 b1 = *(const bf16x8*)&Bs[wc * 32 + 16 + (lane & 15)][kb];
      acc[0][0] = __builtin_amdgcn_mfma_f32_16x16x32_bf16(a0, b0, acc[0][0], 0, 0, 0);
      acc[0][1] = __builtin_amdgcn_mfma_f32_16x16x32_bf16(a0, b1, acc[0][1], 0, 0, 0);
      acc[1][0] = __builtin_amdgcn_mfma_f32_16x16x32_bf16(a1, b0, acc[1][0], 0, 0, 0);
      acc[1][1] = __builtin_amdgcn_mfma_f32_16x16x32_bf16(a1, b1, acc[1][1], 0, 0, 0);
    }
    __syncthreads();
  }

  const int row0 = bm * 64 + wr * 32 + (lane >> 4) * 4;
  const int col0 = bn * 64 + wc * 32 + (lane & 15);
  #pragma unroll
  for (int fm = 0; fm < 2; ++fm)
    #pragma unroll
    for (int fn = 0; fn < 2; ++fn) {
      int n = col0 + fn * 16;
      float bv = bias[n];
      #pragma unroll
      for (int reg = 0; reg < 4; ++reg) {
        size_t off = (size_t)(row0 + fm * 16 + reg) * G3 + n;
        store_ip<IPT>(C + off, acc[fm][fn][reg] + bv);
      }
    }
}

// ---------------------------------------------------------------------------
// fused recurrence: WG 0..15 layer 0, WG 16..31 layer 1.
// Lane (wave=(mh,set), hi=lane>>4, jj=lane&15) owns batch bb = set*16+jj and
// cols cc0..cc0+3, cc0 = p*32 + mh*16 + hi*4, for all 3 gates.
// ---------------------------------------------------------------------------
template <typename IPT>
__global__ __launch_bounds__(256, 1) void gru_fused(
    const IPT* __restrict__ ip0,
    const uint4* __restrict__ bfWh0,
    const float* __restrict__ bh0,
    const uint4* __restrict__ bfWh1,
    const uint4* __restrict__ bfWi1,
    const float* __restrict__ bi1,
    const float* __restrict__ bh1,
    float* __restrict__ y1,
    float* __restrict__ hlast,
    unsigned long long* __restrict__ h0buf,   // [2][32][128] 8B (f16 [32][512])
    unsigned long long* __restrict__ h1buf,   // [2][32][128] 8B
    unsigned long long* __restrict__ y0h,     // [S][32][128] 8B
    unsigned int* __restrict__ fl0,           // [S][16] per-WG flags
    unsigned int* __restrict__ fl1) {         // [S][16]
  __shared__ __align__(16) uint4 wiB[6144];   // L1 only (96 KB)
  const int bid = blockIdx.x, tid = threadIdx.x;
  const int lane = tid & 63, wave = tid >> 6;
  const int set = wave & 1, mh = wave >> 1;
  const int jj = lane & 15, hi = lane >> 4;
  const int bb = set * 16 + jj;               // this lane's batch
  const int bbyte = bb * 1024 + hi * 16;      // h B-frag byte base

  if (bid < NWG) {
    // ======================= layer 0 =======================
    const int p = bid;
    const int cc0 = p * 32 + mh * 16 + hi * 4;     // this lane's col base
    uint4 wf[48];
    {
      const uint4* bsrc = bfWh0 + ((size_t)(p * 2 + mh) * 48) * 64 + lane;
      #pragma unroll
      for (int i = 0; i < 48; ++i) wf[i] = bsrc[i * 64];
    }
    const float4 bhr4 = *(const float4*)(bh0 + cc0);
    const float4 bhz4 = *(const float4*)(bh0 + 512 + cc0);
    const float4 bhn4 = *(const float4*)(bh0 + 1024 + cc0);
    float hfq[4] = {0.f, 0.f, 0.f, 0.f};

    for (int t = 0; t < S_LEN; ++t) {
      // -- ip loads (float4 x3), issued before the poll --
      const IPT* bp = ip0 + ((size_t)bb * S_LEN + t) * G3 + cc0;
      float4 ipr = load_ip4<IPT>(bp);
      float4 ipz = load_ip4<IPT>(bp + 512);
      float4 ipn = load_ip4<IPT>(bp + 1024);
      __builtin_amdgcn_sched_barrier(0);

      if (t > 0) {
        const unsigned int* f = fl0 + (size_t)(t - 1) * NWG;
        while (true) {
          unsigned v = (lane < NWG)
              ? __hip_atomic_load(f + lane, __ATOMIC_RELAXED, __HIP_MEMORY_SCOPE_AGENT)
              : 1u;
          if (__all(v != 0)) break;
          __builtin_amdgcn_s_sleep(1);
        }
      }
      __builtin_amdgcn_sched_barrier(0);

      // -- h B-fragments from LLC (coherent 16B loads) --
      const char* hb = (const char*)h0buf + (t & 1) * 32768 + bbyte;
      uint4 bf[16];
      #pragma unroll
      for (int ks = 0; ks < 16; ++ks)
        asm volatile("global_load_dwordx4 %0, %1, off offset:%2 sc0 sc1"
                     : "=v"(bf[ks]) : "v"(hb), "i"(ks * 64) : "memory");
      asm volatile("s_waitcnt vmcnt(0)" ::: "memory");
      __builtin_amdgcn_sched_barrier(0);

      // -- MFMA: A = weights (gate g), B = h.  acc_g: r,z,n for same (col,bb)
      f32x4 a0 = {}, a1 = {}, a2 = {};
      #pragma unroll
      for (int ks = 0; ks < 16; ++ks) {
        f16x8 hv = __builtin_bit_cast(f16x8, bf[ks]);
        a0 = __builtin_amdgcn_mfma_f32_16x16x32_f16(__builtin_bit_cast(f16x8, wf[ks]),      hv, a0, 0, 0, 0);
        a1 = __builtin_amdgcn_mfma_f32_16x16x32_f16(__builtin_bit_cast(f16x8, wf[16 + ks]), hv, a1, 0, 0, 0);
        a2 = __builtin_amdgcn_mfma_f32_16x16x32_f16(__builtin_bit_cast(f16x8, wf[32 + ks]), hv, a2, 0, 0, 0);
      }

      // -- gates in-register; pack 4 consecutive cols -> one 8B publish --
      unsigned short hx[4];
      #pragma unroll
      for (int q = 0; q < 4; ++q) {
        float rr = sigmoid_f(a0[q] + (&bhr4.x)[q] + (&ipr.x)[q]);
        float zz = sigmoid_f(a1[q] + (&bhz4.x)[q] + (&ipz.x)[q]);
        float nn = tanh_f((&ipn.x)[q] + rr * (a2[q] + (&bhn4.x)[q]));
        float hy = (1.f - zz) * nn + zz * hfq[q];
        hfq[q] = hy;
        hx[q] = __builtin_bit_cast(unsigned short, (_Float16)hy);
      }
      const unsigned long long hw =
          (unsigned long long)hx[0] | ((unsigned long long)hx[1] << 16) |
          ((unsigned long long)hx[2] << 32) | ((unsigned long long)hx[3] << 48);
      const size_t slot = (size_t)bb * 128 + (cc0 >> 2);
      __hip_atomic_store(h0buf + ((size_t)((t + 1) & 1)) * 4096 + slot, hw,
                         __ATOMIC_RELAXED, __HIP_MEMORY_SCOPE_AGENT);
      __hip_atomic_store(y0h + (size_t)t * 4096 + slot, hw,
                         __ATOMIC_RELAXED, __HIP_MEMORY_SCOPE_AGENT);
      asm volatile("s_waitcnt vmcnt(0)" ::: "memory");
      __syncthreads();
      if (tid == 0)
        __hip_atomic_store(fl0 + (size_t)t * NWG + p, 1u,
                           __ATOMIC_RELAXED, __HIP_MEMORY_SCOPE_AGENT);
    }
  } else {
    // ======================= layer 1 =======================
    const int p = bid - NWG;
    const int cc0 = p * 32 + mh * 16 + hi * 4;
    uint4 wf[48];
    {
      const uint4* bsrc = bfWh1 + ((size_t)(p * 2 + mh) * 48) * 64 + lane;
      #pragma unroll
      for (int i = 0; i < 48; ++i) wf[i] = bsrc[i * 64];
    }
    {
      const uint4* src = bfWi1 + (size_t)p * 6144;
      for (int i = tid; i < 6144; i += 256) wiB[i] = src[i];
    }
    const float4 bir4 = *(const float4*)(bi1 + cc0);
    const float4 biz4 = *(const float4*)(bi1 + 512 + cc0);
    const float4 bin4 = *(const float4*)(bi1 + 1024 + cc0);
    const float4 bhr4 = *(const float4*)(bh1 + cc0);
    const float4 bhz4 = *(const float4*)(bh1 + 512 + cc0);
    const float4 bhn4 = *(const float4*)(bh1 + 1024 + cc0);
    float hfq[4] = {0.f, 0.f, 0.f, 0.f};
    const int wb = mh * 3072 + lane;
    __syncthreads();                          // wiB ready (once)

    for (int t = 0; t < S_LEN; ++t) {
      // -- wait layer-0 row t --
      {
        const unsigned int* f = fl0 + (size_t)t * NWG;
        while (true) {
          unsigned v = (lane < NWG)
              ? __hip_atomic_load(f + lane, __ATOMIC_RELAXED, __HIP_MEMORY_SCOPE_AGENT)
              : 1u;
          if (__all(v != 0)) break;
          __builtin_amdgcn_s_sleep(1);
        }
      }
      __builtin_amdgcn_sched_barrier(0);

      // -- y0 row t as B-frags --
      uint4 ay[16];
      {
        const char* yb = (const char*)y0h + (size_t)t * 32768 + bbyte;
        #pragma unroll
        for (int ks = 0; ks < 16; ++ks)
          asm volatile("global_load_dwordx4 %0, %1, off offset:%2 sc0 sc1"
                       : "=v"(ay[ks]) : "v"(yb), "i"(ks * 64) : "memory");
        asm volatile("s_waitcnt vmcnt(0)" ::: "memory");
      }
      __builtin_amdgcn_sched_barrier(0);

      // -- ip1 = Wi1-slice @ y0^T  (A from LDS) --
      f32x4 i0 = {}, i1 = {}, i2 = {};
      #pragma unroll
      for (int ks = 0; ks < 16; ++ks) {
        f16x8 yv = __builtin_bit_cast(f16x8, ay[ks]);
        i0 = __builtin_amdgcn_mfma_f32_16x16x32_f16(__builtin_bit_cast(f16x8, wiB[wb + ks * 64]),        yv, i0, 0, 0, 0);
        i1 = __builtin_amdgcn_mfma_f32_16x16x32_f16(__builtin_bit_cast(f16x8, wiB[wb + (16 + ks) * 64]), yv, i1, 0, 0, 0);
        i2 = __builtin_amdgcn_mfma_f32_16x16x32_f16(__builtin_bit_cast(f16x8, wiB[wb + (32 + ks) * 64]), yv, i2, 0, 0, 0);
      }

      // -- wait own h1(t-1) --
      if (t > 0) {
        const unsigned int* f = fl1 + (size_t)(t - 1) * NWG;
        while (true) {
          unsigned v = (lane < NWG)
              ? __hip_atomic_load(f + lane, __ATOMIC_RELAXED, __HIP_MEMORY_SCOPE_AGENT)
              : 1u;
          if (__all(v != 0)) break;
          __builtin_amdgcn_s_sleep(1);
        }
      }
      __builtin_amdgcn_sched_barrier(0);

      uint4 ah[16];
      {
        const char* hb = (const char*)h1buf + (t & 1) * 32768 + bbyte;
        #pragma unroll
        for (int ks = 0; ks < 16; ++ks)
          asm volatile("global_load_dwordx4 %0, %1, off offset:%2 sc0 sc1"
                       : "=v"(ah[ks]) : "v"(hb), "i"(ks * 64) : "memory");
        asm volatile("s_waitcnt vmcnt(0)" ::: "memory");
      }
      __builtin_amdgcn_sched_barrier(0);

      f32x4 c0 = {}, c1 = {}, c2 = {};
      #pragma unroll
      for (int ks = 0; ks < 16; ++ks) {
        f16x8 hv = __builtin_bit_cast(f16x8, ah[ks]);
        c0 = __builtin_amdgcn_mfma_f32_16x16x32_f16(__builtin_bit_cast(f16x8, wf[ks]),      hv, c0, 0, 0, 0);
        c1 = __builtin_amdgcn_mfma_f32_16x16x32_f16(__builtin_bit_cast(f16x8, wf[16 + ks]), hv, c1, 0, 0, 0);
        c2 = __builtin_amdgcn_mfma_f32_16x16x32_f16(__builtin_bit_cast(f16x8, wf[32 + ks]), hv, c2, 0, 0, 0);
      }

      // -- gates in-register; publish h1 (one 8B store) --
      float hyv[4];
      unsigned short hx[4];
      #pragma unroll
      for (int q = 0; q < 4; ++q) {
        float rr = sigmoid_f(i0[q] + c0[q] + (&bir4.x)[q] + (&bhr4.x)[q]);
        float zz = sigmoid_f(i1[q] + c1[q] + (&biz4.x)[q] + (&bhz4.x)[q]);
        float nn = tanh_f((i2[q] + (&bin4.x)[q]) + rr * (c2[q] + (&bhn4.x)[q]));
        float hy = (1.f - zz) * nn + zz * hfq[q];
        hfq[q] = hy;
        hyv[q] = hy;
        hx[q] = __builtin_bit_cast(unsigned short, (_Float16)hy);
      }
      const unsigned long long hw =
          (unsigned long long)hx[0] | ((unsigned long long)hx[1] << 16) |
          ((unsigned long long)hx[2] << 32) | ((unsigned long long)hx[3] << 48);
      __hip_atomic_store(h1buf + ((size_t)((t + 1) & 1)) * 4096 + (size_t)bb * 128 + (cc0 >> 2),
                         hw, __ATOMIC_RELAXED, __HIP_MEMORY_SCOPE_AGENT);
      asm volatile("s_waitcnt vmcnt(0)" ::: "memory");
      __syncthreads();
      if (tid == 0)
        __hip_atomic_store(fl1 + (size_t)t * NWG + p, 1u,
                           __ATOMIC_RELAXED, __HIP_MEMORY_SCOPE_AGENT);

      // -- y1 float4 store, off the critical path --
      float4 yo = { hyv[0], hyv[1], hyv[2], hyv[3] };
      *(float4*)(y1 + ((size_t)bb * S_LEN + t) * HID + cc0) = yo;
      if (t == S_LEN - 1)
        *(float4*)(hlast + (size_t)bb * HID + cc0) = yo;
    }
  }
}

// ---------------------------------------------------------------------------
// ws layout (bytes)
// ---------------------------------------------------------------------------
#define BFWH0_OFF 0ull
#define BFWH1_OFF 1572864ull
#define BFWI1_OFF 3145728ull
#define WI0_OFF   4718592ull
#define H0_OFF    6291456ull      // 65536
#define H1_OFF    6356992ull      // 65536
#define FL0_OFF   6422528ull      // 131072 ([2048][16] dwords)
#define FL1_OFF   6553600ull      // 131072
#define Y0H_OFF   6684672ull      // 67108864
#define IP_OFF    73793536ull

template <typename IPT>
static void run_all(const float* x,
                    const float* Wi0, const float* bi0, const float* Wh0, const float* bh0,
                    const float* Wi1, const float* bi1, const float* Wh1, const float* bh1,
                    float* out, char* ws, hipStream_t stream) {
  unsigned int* bfWh0 = (unsigned int*)(ws + BFWH0_OFF);
  unsigned int* bfWh1 = (unsigned int*)(ws + BFWH1_OFF);
  unsigned int* bfWi1 = (unsigned int*)(ws + BFWI1_OFF);
  __bf16* wi0b = (__bf16*)(ws + WI0_OFF);
  unsigned long long* h0buf = (unsigned long long*)(ws + H0_OFF);
  unsigned long long* h1buf = (unsigned long long*)(ws + H1_OFF);
  unsigned int* fl0 = (unsigned int*)(ws + FL0_OFF);
  unsigned int* fl1 = (unsigned int*)(ws + FL1_OFF);
  unsigned long long* y0h = (unsigned long long*)(ws + Y0H_OFF);
  IPT* ip = (IPT*)(ws + IP_OFF);
  float* y1    = out;
  float* hlast = out + (size_t)MROWS * HID;

  // zero h bufs + both flag arrays (contiguous region) each launch
  hipMemsetAsync(ws + H0_OFF, 0, 65536 + 65536 + 131072 + 131072, stream);

  prep_bfrag<<<dim3(1536), dim3(256), 0, stream>>>(Wh0, bfWh0);
  prep_bfrag<<<dim3(1536), dim3(256), 0, stream>>>(Wh1, bfWh1);
  prep_bfrag<<<dim3(1536), dim3(256), 0, stream>>>(Wi1, bfWi1);
  prep_wib<<<dim3(3072), dim3(256), 0, stream>>>(Wi0, wi0b);

  gemm_ip<IPT><<<dim3(24, 1024), dim3(256), 0, stream>>>(x, wi0b, bi0, ip);
  gru_fused<IPT><<<dim3(2 * NWG), dim3(256), 0, stream>>>(
      ip, (const uint4*)bfWh0, bh0, (const uint4*)bfWh1, (const uint4*)bfWi1,
      bi1, bh1, y1, hlast, h0buf, h1buf, y0h, fl0, fl1);
}

extern "C" void kernel_launch(void* const* d_in, const int* in_sizes, int n_in,
                              void* d_out, int out_size, void* d_ws, size_t ws_size,
                              hipStream_t stream) {
  const float* x   = (const float*)d_in[0];
  const float* Wi0 = (const float*)d_in[1];
  const float* bi0 = (const float*)d_in[2];
  const float* Wh0 = (const float*)d_in[3];
  const float* bh0 = (const float*)d_in[4];
  const float* Wi1 = (const float*)d_in[5];
  const float* bi1 = (const float*)d_in[6];
  const float* Wh1 = (const float*)d_in[7];
  const float* bh1 = (const float*)d_in[8];
  float* out = (float*)d_out;
  char*  ws  = (char*)d_ws;

  const size_t need_f32 = IP_OFF + (size_t)MROWS * G3 * 4;
  if (ws_size >= need_f32) {
    run_all<float>(x, Wi0, bi0, Wh0, bh0, Wi1, bi1, Wh1, bh1, out, ws, stream);
  } else {
    run_all<unsigned short>(x, Wi0, bi0, Wh0, bh0, Wi1, bi1, Wh1, bh1, out, ws, stream);
  }
}

// Round 10
// 13661.621 us; speedup vs baseline: 3.5077x; 1.0001x over previous
//
#include <hip/hip_runtime.h>
#include <hip/hip_bf16.h>

// ---------------------------------------------------------------------------
// GRU, 2 layers, B=32, S=2048, D=H=512.
//   gemm:   ip0 = x @ Wi0^T + bi0   (bf16 MFMA)                [verified]
//   fused:  32 WGs. WG 0..15 = layer-0 rec, WG 16..31 = layer-1 rec.
//   r10 = r7 (passing, 13.26 ms) + ONE change: weight fragments pinned in
//   VGPRs via opaque no-op asm, applied PER 32-BIT COMPONENT (r9's whole-
//   uint4 "+v" hit "tied indirect register inputs" in the backend).
//   r7's VGPR_Count=168 < 192 proved wf[] was scratch/refetched each step.
//   Everything else (sync protocol, publish, loads) is byte-for-byte r7.
// ---------------------------------------------------------------------------

typedef __bf16    bf16x8 __attribute__((ext_vector_type(8)));
typedef __bf16    bf16x4 __attribute__((ext_vector_type(4)));
typedef float     f32x4  __attribute__((ext_vector_type(4)));
typedef _Float16  f16x2  __attribute__((ext_vector_type(2)));
typedef _Float16  f16x8  __attribute__((ext_vector_type(8)));

#define S_LEN 2048
#define BATCH 32
#define HID   512
#define G3    1536
#define MROWS (BATCH * S_LEN)
#define NWG   16

__device__ inline float sigmoid_f(float x) { return 1.f / (1.f + __expf(-x)); }
__device__ inline float tanh_f(float x) {
  float e = __expf(2.f * x);
  return 1.f - 2.f / (e + 1.f);
}

template <typename IPT>
__device__ inline void store_ip(IPT* p, float v) {
  if constexpr (sizeof(IPT) == 4) *p = v;
  else *p = __builtin_bit_cast(unsigned short, (__bf16)v);
}
template <typename IPT>
__device__ inline float4 load_ip4(const IPT* p) {
  if constexpr (sizeof(IPT) == 4) {
    return *(const float4*)p;
  } else {
    ushort4 u = *(const ushort4*)p;
    float4 r;
    r.x = __uint_as_float((unsigned)u.x << 16);
    r.y = __uint_as_float((unsigned)u.y << 16);
    r.z = __uint_as_float((unsigned)u.z << 16);
    r.w = __uint_as_float((unsigned)u.w << 16);
    return r;
  }
}

// ---------------------------------------------------------------------------
// prep: Wi0 fp32 -> bf16 (for ip GEMM)
// ---------------------------------------------------------------------------
__global__ void prep_wib(const float* __restrict__ W, __bf16* __restrict__ o) {
  int i = blockIdx.x * 256 + threadIdx.x;
  o[i] = (__bf16)W[i];
}

// ---------------------------------------------------------------------------
// prep: (1536,512) fp32 weight -> A-fragment order (f16 pairs), operand-swap.
// A-frag (16x16x32): lane l holds A[row][k], row = l&15, k = ks*32+(l>>4)*8+e.
// Tile (p, mh, g): A rows = g*512 + p*32 + mh*16 + (l&15).
//   dword idx = ((p*2+mh)*48 + g*16 + ks)*256 + l*4 + d ; k = ks*32+(l>>4)*8+2d
// ---------------------------------------------------------------------------
__global__ void prep_bfrag(const float* __restrict__ W, unsigned int* __restrict__ out) {
  int idx = blockIdx.x * 256 + threadIdx.x;   // grid = 393216/256 = 1536
  int p    = idx / 24576;
  int r    = idx % 24576;
  int mh   = r / 12288;
  int r2   = r % 12288;
  int frag = r2 / 256;                        // g*16 + ks
  int lq   = r2 % 256;
  int l    = lq >> 2, d = lq & 3;
  int g    = frag >> 4, ks = frag & 15;
  int row  = g * 512 + p * 32 + mh * 16 + (l & 15);
  int k    = ks * 32 + (l >> 4) * 8 + 2 * d;
  f16x2 pk = { (_Float16)W[(size_t)row * HID + k],
               (_Float16)W[(size_t)row * HID + k + 1] };
  out[idx] = __builtin_bit_cast(unsigned int, pk);
}

// ---------------------------------------------------------------------------
// ip GEMM (verified): C(M,1536)=A(M,512)@Bw(1536,512)^T + bias
// ---------------------------------------------------------------------------
template <typename IPT>
__global__ __launch_bounds__(256) void gemm_ip(
    const float* __restrict__ A, const __bf16* __restrict__ Bw,
    const float* __restrict__ bias, IPT* __restrict__ C) {
  constexpr int K = 512;
  __shared__ __align__(16) __bf16 As[64][72];
  __shared__ __align__(16) __bf16 Bs[64][72];
  const int tid  = threadIdx.x;
  const int bm   = blockIdx.y, bn = blockIdx.x;
  const int lane = tid & 63,  wave = tid >> 6;
  const int wr   = wave >> 1, wc   = wave & 1;
  f32x4 acc[2][2] = {};
  const int r = tid >> 2, q = tid & 3;
  const float*  Arow = A  + (size_t)(bm * 64 + r) * K;
  const __bf16* Brow = Bw + (size_t)(bn * 64 + r) * K;

  for (int k0 = 0; k0 < K; k0 += 64) {
    const float4* as = (const float4*)(Arow + k0);
    #pragma unroll
    for (int i = 0; i < 4; ++i) {
      float4 v = as[q + 4 * i];
      bf16x4 pkt = { (__bf16)v.x, (__bf16)v.y, (__bf16)v.z, (__bf16)v.w };
      *(bf16x4*)&As[r][4 * (q + 4 * i)] = pkt;
    }
    const uint4* bs = (const uint4*)(Brow + k0);
    uint4* bd = (uint4*)&Bs[r][0];
    bd[q]     = bs[q];
    bd[q + 4] = bs[q + 4];
    __syncthreads();

    #pragma unroll
    for (int kk = 0; kk < 64; kk += 32) {
      const int kb = kk + 8 * (lane >> 4);
      bf16x8 a0 = *(const bf16x8*)&As[wr * 32 +      (lane & 15)][kb];
      bf16x8 a1 = *(const bf16x8*)&As[wr * 32 + 16 + (lane & 15)][kb];
      bf16x8 b0 = *(const bf16x8*)&Bs[wc * 32 +      (lane & 15)][kb];
      bf16x8 b1 = *(const bf16x8*)&Bs[wc * 32 + 16 + (lane & 15)][kb];
      acc[0][0] = __builtin_amdgcn_mfma_f32_16x16x32_bf16(a0, b0, acc[0][0], 0, 0, 0);
      acc[0][1] = __builtin_amdgcn_mfma_f32_16x16x32_bf16(a0, b1, acc[0][1], 0, 0, 0);
      acc[1][0] = __builtin_amdgcn_mfma_f32_16x16x32_bf16(a1, b0, acc[1][0], 0, 0, 0);
      acc[1][1] = __builtin_amdgcn_mfma_f32_16x16x32_bf16(a1, b1, acc[1][1], 0, 0, 0);
    }
    __syncthreads();
  }

  const int row0 = bm * 64 + wr * 32 + (lane >> 4) * 4;
  const int col0 = bn * 64 + wc * 32 + (lane & 15);
  #pragma unroll
  for (int fm = 0; fm < 2; ++fm)
    #pragma unroll
    for (int fn = 0; fn < 2; ++fn) {
      int n = col0 + fn * 16;
      float bv = bias[n];
      #pragma unroll
      for (int reg = 0; reg < 4; ++reg) {
        size_t off = (size_t)(row0 + fm * 16 + reg) * G3 + n;
        store_ip<IPT>(C + off, acc[fm][fn][reg] + bv);
      }
    }
}

// ---------------------------------------------------------------------------
// fused recurrence: WG 0..15 layer 0, WG 16..31 layer 1.
// Lane (wave=(mh,set), hi=lane>>4, jj=lane&15) owns batch bb = set*16+jj and
// cols cc0..cc0+3, cc0 = p*32 + mh*16 + hi*4, for all 3 gates.
// ---------------------------------------------------------------------------
template <typename IPT>
__global__ __launch_bounds__(256, 1) void gru_fused(
    const IPT* __restrict__ ip0,
    const uint4* __restrict__ bfWh0,
    const float* __restrict__ bh0,
    const uint4* __restrict__ bfWh1,
    const uint4* __restrict__ bfWi1,
    const float* __restrict__ bi1,
    const float* __restrict__ bh1,
    float* __restrict__ y1,
    float* __restrict__ hlast,
    unsigned long long* __restrict__ h0buf,   // [2][32][128] 8B (f16 [32][512])
    unsigned long long* __restrict__ h1buf,   // [2][32][128] 8B
    unsigned long long* __restrict__ y0h,     // [S][32][128] 8B
    unsigned int* __restrict__ fl0,           // [S][16] per-WG flags
    unsigned int* __restrict__ fl1) {         // [S][16]
  __shared__ __align__(16) uint4 wiB[6144];   // L1 only (96 KB)
  const int bid = blockIdx.x, tid = threadIdx.x;
  const int lane = tid & 63, wave = tid >> 6;
  const int set = wave & 1, mh = wave >> 1;
  const int jj = lane & 15, hi = lane >> 4;
  const int bb = set * 16 + jj;               // this lane's batch
  const int bbyte = bb * 1024 + hi * 16;      // h B-frag byte base

  if (bid < NWG) {
    // ======================= layer 0 =======================
    const int p = bid;
    const int cc0 = p * 32 + mh * 16 + hi * 4;     // this lane's col base
    uint4 wf[48];
    {
      const uint4* bsrc = bfWh0 + ((size_t)(p * 2 + mh) * 48) * 64 + lane;
      #pragma unroll
      for (int i = 0; i < 48; ++i) wf[i] = bsrc[i * 64];
      // r10: pin fragments in VGPRs, per 32-bit component (kills remat/spill)
      #pragma unroll
      for (int i = 0; i < 48; ++i)
        asm volatile("" : "+v"(wf[i].x), "+v"(wf[i].y), "+v"(wf[i].z), "+v"(wf[i].w));
    }
    const float4 bhr4 = *(const float4*)(bh0 + cc0);
    const float4 bhz4 = *(const float4*)(bh0 + 512 + cc0);
    const float4 bhn4 = *(const float4*)(bh0 + 1024 + cc0);
    float hfq[4] = {0.f, 0.f, 0.f, 0.f};

    for (int t = 0; t < S_LEN; ++t) {
      // -- ip loads (float4 x3), issued before the poll --
      const IPT* bp = ip0 + ((size_t)bb * S_LEN + t) * G3 + cc0;
      float4 ipr = load_ip4<IPT>(bp);
      float4 ipz = load_ip4<IPT>(bp + 512);
      float4 ipn = load_ip4<IPT>(bp + 1024);
      __builtin_amdgcn_sched_barrier(0);

      if (t > 0) {
        const unsigned int* f = fl0 + (size_t)(t - 1) * NWG;
        while (true) {
          unsigned v = (lane < NWG)
              ? __hip_atomic_load(f + lane, __ATOMIC_RELAXED, __HIP_MEMORY_SCOPE_AGENT)
              : 1u;
          if (__all(v != 0)) break;
          __builtin_amdgcn_s_sleep(1);
        }
      }
      __builtin_amdgcn_sched_barrier(0);

      // -- h B-fragments from LLC (coherent 16B loads) --
      const char* hb = (const char*)h0buf + (t & 1) * 32768 + bbyte;
      uint4 bf[16];
      #pragma unroll
      for (int ks = 0; ks < 16; ++ks)
        asm volatile("global_load_dwordx4 %0, %1, off offset:%2 sc0 sc1"
                     : "=v"(bf[ks]) : "v"(hb), "i"(ks * 64) : "memory");
      asm volatile("s_waitcnt vmcnt(0)" ::: "memory");
      __builtin_amdgcn_sched_barrier(0);

      // -- MFMA: A = weights (gate g), B = h.  acc_g: r,z,n for same (col,bb)
      f32x4 a0 = {}, a1 = {}, a2 = {};
      #pragma unroll
      for (int ks = 0; ks < 16; ++ks) {
        f16x8 hv = __builtin_bit_cast(f16x8, bf[ks]);
        a0 = __builtin_amdgcn_mfma_f32_16x16x32_f16(__builtin_bit_cast(f16x8, wf[ks]),      hv, a0, 0, 0, 0);
        a1 = __builtin_amdgcn_mfma_f32_16x16x32_f16(__builtin_bit_cast(f16x8, wf[16 + ks]), hv, a1, 0, 0, 0);
        a2 = __builtin_amdgcn_mfma_f32_16x16x32_f16(__builtin_bit_cast(f16x8, wf[32 + ks]), hv, a2, 0, 0, 0);
      }

      // -- gates in-register; pack 4 consecutive cols -> one 8B publish --
      unsigned short hx[4];
      #pragma unroll
      for (int q = 0; q < 4; ++q) {
        float rr = sigmoid_f(a0[q] + (&bhr4.x)[q] + (&ipr.x)[q]);
        float zz = sigmoid_f(a1[q] + (&bhz4.x)[q] + (&ipz.x)[q]);
        float nn = tanh_f((&ipn.x)[q] + rr * (a2[q] + (&bhn4.x)[q]));
        float hy = (1.f - zz) * nn + zz * hfq[q];
        hfq[q] = hy;
        hx[q] = __builtin_bit_cast(unsigned short, (_Float16)hy);
      }
      const unsigned long long hw =
          (unsigned long long)hx[0] | ((unsigned long long)hx[1] << 16) |
          ((unsigned long long)hx[2] << 32) | ((unsigned long long)hx[3] << 48);
      const size_t slot = (size_t)bb * 128 + (cc0 >> 2);
      __hip_atomic_store(h0buf + ((size_t)((t + 1) & 1)) * 4096 + slot, hw,
                         __ATOMIC_RELAXED, __HIP_MEMORY_SCOPE_AGENT);
      __hip_atomic_store(y0h + (size_t)t * 4096 + slot, hw,
                         __ATOMIC_RELAXED, __HIP_MEMORY_SCOPE_AGENT);
      asm volatile("s_waitcnt vmcnt(0)" ::: "memory");
      __syncthreads();
      if (tid == 0)
        __hip_atomic_store(fl0 + (size_t)t * NWG + p, 1u,
                           __ATOMIC_RELAXED, __HIP_MEMORY_SCOPE_AGENT);
    }
  } else {
    // ======================= layer 1 =======================
    const int p = bid - NWG;
    const int cc0 = p * 32 + mh * 16 + hi * 4;
    uint4 wf[48];
    {
      const uint4* bsrc = bfWh1 + ((size_t)(p * 2 + mh) * 48) * 64 + lane;
      #pragma unroll
      for (int i = 0; i < 48; ++i) wf[i] = bsrc[i * 64];
      // r10: pin fragments in VGPRs, per 32-bit component
      #pragma unroll
      for (int i = 0; i < 48; ++i)
        asm volatile("" : "+v"(wf[i].x), "+v"(wf[i].y), "+v"(wf[i].z), "+v"(wf[i].w));
    }
    {
      const uint4* src = bfWi1 + (size_t)p * 6144;
      for (int i = tid; i < 6144; i += 256) wiB[i] = src[i];
    }
    const float4 bir4 = *(const float4*)(bi1 + cc0);
    const float4 biz4 = *(const float4*)(bi1 + 512 + cc0);
    const float4 bin4 = *(const float4*)(bi1 + 1024 + cc0);
    const float4 bhr4 = *(const float4*)(bh1 + cc0);
    const float4 bhz4 = *(const float4*)(bh1 + 512 + cc0);
    const float4 bhn4 = *(const float4*)(bh1 + 1024 + cc0);
    float hfq[4] = {0.f, 0.f, 0.f, 0.f};
    const int wb = mh * 3072 + lane;
    __syncthreads();                          // wiB ready (once)

    for (int t = 0; t < S_LEN; ++t) {
      // -- wait layer-0 row t --
      {
        const unsigned int* f = fl0 + (size_t)t * NWG;
        while (true) {
          unsigned v = (lane < NWG)
              ? __hip_atomic_load(f + lane, __ATOMIC_RELAXED, __HIP_MEMORY_SCOPE_AGENT)
              : 1u;
          if (__all(v != 0)) break;
          __builtin_amdgcn_s_sleep(1);
        }
      }
      __builtin_amdgcn_sched_barrier(0);

      // -- y0 row t as B-frags --
      uint4 ay[16];
      {
        const char* yb = (const char*)y0h + (size_t)t * 32768 + bbyte;
        #pragma unroll
        for (int ks = 0; ks < 16; ++ks)
          asm volatile("global_load_dwordx4 %0, %1, off offset:%2 sc0 sc1"
                       : "=v"(ay[ks]) : "v"(yb), "i"(ks * 64) : "memory");
        asm volatile("s_waitcnt vmcnt(0)" ::: "memory");
      }
      __builtin_amdgcn_sched_barrier(0);

      // -- ip1 = Wi1-slice @ y0^T  (A from LDS) --
      f32x4 i0 = {}, i1 = {}, i2 = {};
      #pragma unroll
      for (int ks = 0; ks < 16; ++ks) {
        f16x8 yv = __builtin_bit_cast(f16x8, ay[ks]);
        i0 = __builtin_amdgcn_mfma_f32_16x16x32_f16(__builtin_bit_cast(f16x8, wiB[wb + ks * 64]),        yv, i0, 0, 0, 0);
        i1 = __builtin_amdgcn_mfma_f32_16x16x32_f16(__builtin_bit_cast(f16x8, wiB[wb + (16 + ks) * 64]), yv, i1, 0, 0, 0);
        i2 = __builtin_amdgcn_mfma_f32_16x16x32_f16(__builtin_bit_cast(f16x8, wiB[wb + (32 + ks) * 64]), yv, i2, 0, 0, 0);
      }

      // -- wait own h1(t-1) --
      if (t > 0) {
        const unsigned int* f = fl1 + (size_t)(t - 1) * NWG;
        while (true) {
          unsigned v = (lane < NWG)
              ? __hip_atomic_load(f + lane, __ATOMIC_RELAXED, __HIP_MEMORY_SCOPE_AGENT)
              : 1u;
          if (__all(v != 0)) break;
          __builtin_amdgcn_s_sleep(1);
        }
      }
      __builtin_amdgcn_sched_barrier(0);

      uint4 ah[16];
      {
        const char* hb = (const char*)h1buf + (t & 1) * 32768 + bbyte;
        #pragma unroll
        for (int ks = 0; ks < 16; ++ks)
          asm volatile("global_load_dwordx4 %0, %1, off offset:%2 sc0 sc1"
                       : "=v"(ah[ks]) : "v"(hb), "i"(ks * 64) : "memory");
        asm volatile("s_waitcnt vmcnt(0)" ::: "memory");
      }
      __builtin_amdgcn_sched_barrier(0);

      f32x4 c0 = {}, c1 = {}, c2 = {};
      #pragma unroll
      for (int ks = 0; ks < 16; ++ks) {
        f16x8 hv = __builtin_bit_cast(f16x8, ah[ks]);
        c0 = __builtin_amdgcn_mfma_f32_16x16x32_f16(__builtin_bit_cast(f16x8, wf[ks]),      hv, c0, 0, 0, 0);
        c1 = __builtin_amdgcn_mfma_f32_16x16x32_f16(__builtin_bit_cast(f16x8, wf[16 + ks]), hv, c1, 0, 0, 0);
        c2 = __builtin_amdgcn_mfma_f32_16x16x32_f16(__builtin_bit_cast(f16x8, wf[32 + ks]), hv, c2, 0, 0, 0);
      }

      // -- gates in-register; publish h1 (one 8B store) --
      float hyv[4];
      unsigned short hx[4];
      #pragma unroll
      for (int q = 0; q < 4; ++q) {
        float rr = sigmoid_f(i0[q] + c0[q] + (&bir4.x)[q] + (&bhr4.x)[q]);
        float zz = sigmoid_f(i1[q] + c1[q] + (&biz4.x)[q] + (&bhz4.x)[q]);
        float nn = tanh_f((i2[q] + (&bin4.x)[q]) + rr * (c2[q] + (&bhn4.x)[q]));
        float hy = (1.f - zz) * nn + zz * hfq[q];
        hfq[q] = hy;
        hyv[q] = hy;
        hx[q] = __builtin_bit_cast(unsigned short, (_Float16)hy);
      }
      const unsigned long long hw =
          (unsigned long long)hx[0] | ((unsigned long long)hx[1] << 16) |
          ((unsigned long long)hx[2] << 32) | ((unsigned long long)hx[3] << 48);
      __hip_atomic_store(h1buf + ((size_t)((t + 1) & 1)) * 4096 + (size_t)bb * 128 + (cc0 >> 2),
                         hw, __ATOMIC_RELAXED, __HIP_MEMORY_SCOPE_AGENT);
      asm volatile("s_waitcnt vmcnt(0)" ::: "memory");
      __syncthreads();
      if (tid == 0)
        __hip_atomic_store(fl1 + (size_t)t * NWG + p, 1u,
                           __ATOMIC_RELAXED, __HIP_MEMORY_SCOPE_AGENT);

      // -- y1 float4 store, off the critical path --
      float4 yo = { hyv[0], hyv[1], hyv[2], hyv[3] };
      *(float4*)(y1 + ((size_t)bb * S_LEN + t) * HID + cc0) = yo;
      if (t == S_LEN - 1)
        *(float4*)(hlast + (size_t)bb * HID + cc0) = yo;
    }
  }
}

// ---------------------------------------------------------------------------
// ws layout (bytes)
// ---------------------------------------------------------------------------
#define BFWH0_OFF 0ull
#define BFWH1_OFF 1572864ull
#define BFWI1_OFF 3145728ull
#define WI0_OFF   4718592ull
#define H0_OFF    6291456ull      // 65536
#define H1_OFF    6356992ull      // 65536
#define FL0_OFF   6422528ull      // 131072 ([2048][16] dwords)
#define FL1_OFF   6553600ull      // 131072
#define Y0H_OFF   6684672ull      // 67108864
#define IP_OFF    73793536ull

template <typename IPT>
static void run_all(const float* x,
                    const float* Wi0, const float* bi0, const float* Wh0, const float* bh0,
                    const float* Wi1, const float* bi1, const float* Wh1, const float* bh1,
                    float* out, char* ws, hipStream_t stream) {
  unsigned int* bfWh0 = (unsigned int*)(ws + BFWH0_OFF);
  unsigned int* bfWh1 = (unsigned int*)(ws + BFWH1_OFF);
  unsigned int* bfWi1 = (unsigned int*)(ws + BFWI1_OFF);
  __bf16* wi0b = (__bf16*)(ws + WI0_OFF);
  unsigned long long* h0buf = (unsigned long long*)(ws + H0_OFF);
  unsigned long long* h1buf = (unsigned long long*)(ws + H1_OFF);
  unsigned int* fl0 = (unsigned int*)(ws + FL0_OFF);
  unsigned int* fl1 = (unsigned int*)(ws + FL1_OFF);
  unsigned long long* y0h = (unsigned long long*)(ws + Y0H_OFF);
  IPT* ip = (IPT*)(ws + IP_OFF);
  float* y1    = out;
  float* hlast = out + (size_t)MROWS * HID;

  // zero h bufs + both flag arrays (contiguous region) each launch
  hipMemsetAsync(ws + H0_OFF, 0, 65536 + 65536 + 131072 + 131072, stream);

  prep_bfrag<<<dim3(1536), dim3(256), 0, stream>>>(Wh0, bfWh0);
  prep_bfrag<<<dim3(1536), dim3(256), 0, stream>>>(Wh1, bfWh1);
  prep_bfrag<<<dim3(1536), dim3(256), 0, stream>>>(Wi1, bfWi1);
  prep_wib<<<dim3(3072), dim3(256), 0, stream>>>(Wi0, wi0b);

  gemm_ip<IPT><<<dim3(24, 1024), dim3(256), 0, stream>>>(x, wi0b, bi0, ip);
  gru_fused<IPT><<<dim3(2 * NWG), dim3(256), 0, stream>>>(
      ip, (const uint4*)bfWh0, bh0, (const uint4*)bfWh1, (const uint4*)bfWi1,
      bi1, bh1, y1, hlast, h0buf, h1buf, y0h, fl0, fl1);
}

extern "C" void kernel_launch(void* const* d_in, const int* in_sizes, int n_in,
                              void* d_out, int out_size, void* d_ws, size_t ws_size,
                              hipStream_t stream) {
  const float* x   = (const float*)d_in[0];
  const float* Wi0 = (const float*)d_in[1];
  const float* bi0 = (const float*)d_in[2];
  const float* Wh0 = (const float*)d_in[3];
  const float* bh0 = (const float*)d_in[4];
  const float* Wi1 = (const float*)d_in[5];
  const float* bi1 = (const float*)d_in[6];
  const float* Wh1 = (const float*)d_in[7];
  const float* bh1 = (const float*)d_in[8];
  float* out = (float*)d_out;
  char*  ws  = (char*)d_ws;

  const size_t need_f32 = IP_OFF + (size_t)MROWS * G3 * 4;
  if (ws_size >= need_f32) {
    run_all<float>(x, Wi0, bi0, Wh0, bh0, Wi1, bi1, Wh1, bh1, out, ws, stream);
  } else {
    run_all<unsigned short>(x, Wi0, bi0, Wh0, bh0, Wi1, bi1, Wh1, bh1, out, ws, stream);
  }
}

// Round 13
// 13612.822 us; speedup vs baseline: 3.5202x; 1.0036x over previous
//
#include <hip/hip_runtime.h>
#include <hip/hip_bf16.h>

// ---------------------------------------------------------------------------
// GRU, 2 layers, B=32, S=2048, D=H=512.
//   gemm:   ip0 = x @ Wi0^T + bi0   (bf16 MFMA)                [verified]
//   fused:  32 WGs. WG 0..15 = layer-0 rec, WG 16..31 = layer-1 rec.
//   r13 = r10 (passing, 13.66 ms, flag protocol) + ONE change: L1's ip1
//   block (poll fl0 + ay load + 48 MFMA) moved to a SHADOW phase after
//   fl1[t] is signaled, computing ip1 for t+1 during the window where other
//   L1 WGs finish step t. L0 and the entire sync vocabulary are byte-for-
//   byte r10. Deadlock-free: L0 never waits on L1; L1 sets fl1[t] before
//   polling fl0[t+1]. r11/r12's flag-free poison dataflow is abandoned
//   (NaN with unidentified mechanism after 2 attempts).
// ---------------------------------------------------------------------------

typedef __bf16    bf16x8 __attribute__((ext_vector_type(8)));
typedef __bf16    bf16x4 __attribute__((ext_vector_type(4)));
typedef float     f32x4  __attribute__((ext_vector_type(4)));
typedef _Float16  f16x2  __attribute__((ext_vector_type(2)));
typedef _Float16  f16x8  __attribute__((ext_vector_type(8)));

#define S_LEN 2048
#define BATCH 32
#define HID   512
#define G3    1536
#define MROWS (BATCH * S_LEN)
#define NWG   16

__device__ inline float sigmoid_f(float x) { return 1.f / (1.f + __expf(-x)); }
__device__ inline float tanh_f(float x) {
  float e = __expf(2.f * x);
  return 1.f - 2.f / (e + 1.f);
}

template <typename IPT>
__device__ inline void store_ip(IPT* p, float v) {
  if constexpr (sizeof(IPT) == 4) *p = v;
  else *p = __builtin_bit_cast(unsigned short, (__bf16)v);
}
template <typename IPT>
__device__ inline float4 load_ip4(const IPT* p) {
  if constexpr (sizeof(IPT) == 4) {
    return *(const float4*)p;
  } else {
    ushort4 u = *(const ushort4*)p;
    float4 r;
    r.x = __uint_as_float((unsigned)u.x << 16);
    r.y = __uint_as_float((unsigned)u.y << 16);
    r.z = __uint_as_float((unsigned)u.z << 16);
    r.w = __uint_as_float((unsigned)u.w << 16);
    return r;
  }
}

// ---------------------------------------------------------------------------
// prep: Wi0 fp32 -> bf16 (for ip GEMM)
// ---------------------------------------------------------------------------
__global__ void prep_wib(const float* __restrict__ W, __bf16* __restrict__ o) {
  int i = blockIdx.x * 256 + threadIdx.x;
  o[i] = (__bf16)W[i];
}

// ---------------------------------------------------------------------------
// prep: (1536,512) fp32 weight -> A-fragment order (f16 pairs), operand-swap.
// A-frag (16x16x32): lane l holds A[row][k], row = l&15, k = ks*32+(l>>4)*8+e.
// Tile (p, mh, g): A rows = g*512 + p*32 + mh*16 + (l&15).
//   dword idx = ((p*2+mh)*48 + g*16 + ks)*256 + l*4 + d ; k = ks*32+(l>>4)*8+2d
// ---------------------------------------------------------------------------
__global__ void prep_bfrag(const float* __restrict__ W, unsigned int* __restrict__ out) {
  int idx = blockIdx.x * 256 + threadIdx.x;   // grid = 393216/256 = 1536
  int p    = idx / 24576;
  int r    = idx % 24576;
  int mh   = r / 12288;
  int r2   = r % 12288;
  int frag = r2 / 256;                        // g*16 + ks
  int lq   = r2 % 256;
  int l    = lq >> 2, d = lq & 3;
  int g    = frag >> 4, ks = frag & 15;
  int row  = g * 512 + p * 32 + mh * 16 + (l & 15);
  int k    = ks * 32 + (l >> 4) * 8 + 2 * d;
  f16x2 pk = { (_Float16)W[(size_t)row * HID + k],
               (_Float16)W[(size_t)row * HID + k + 1] };
  out[idx] = __builtin_bit_cast(unsigned int, pk);
}

// ---------------------------------------------------------------------------
// ip GEMM (verified): C(M,1536)=A(M,512)@Bw(1536,512)^T + bias
// ---------------------------------------------------------------------------
template <typename IPT>
__global__ __launch_bounds__(256) void gemm_ip(
    const float* __restrict__ A, const __bf16* __restrict__ Bw,
    const float* __restrict__ bias, IPT* __restrict__ C) {
  constexpr int K = 512;
  __shared__ __align__(16) __bf16 As[64][72];
  __shared__ __align__(16) __bf16 Bs[64][72];
  const int tid  = threadIdx.x;
  const int bm   = blockIdx.y, bn = blockIdx.x;
  const int lane = tid & 63,  wave = tid >> 6;
  const int wr   = wave >> 1, wc   = wave & 1;
  f32x4 acc[2][2] = {};
  const int r = tid >> 2, q = tid & 3;
  const float*  Arow = A  + (size_t)(bm * 64 + r) * K;
  const __bf16* Brow = Bw + (size_t)(bn * 64 + r) * K;

  for (int k0 = 0; k0 < K; k0 += 64) {
    const float4* as = (const float4*)(Arow + k0);
    #pragma unroll
    for (int i = 0; i < 4; ++i) {
      float4 v = as[q + 4 * i];
      bf16x4 pkt = { (__bf16)v.x, (__bf16)v.y, (__bf16)v.z, (__bf16)v.w };
      *(bf16x4*)&As[r][4 * (q + 4 * i)] = pkt;
    }
    const uint4* bs = (const uint4*)(Brow + k0);
    uint4* bd = (uint4*)&Bs[r][0];
    bd[q]     = bs[q];
    bd[q + 4] = bs[q + 4];
    __syncthreads();

    #pragma unroll
    for (int kk = 0; kk < 64; kk += 32) {
      const int kb = kk + 8 * (lane >> 4);
      bf16x8 a0 = *(const bf16x8*)&As[wr * 32 +      (lane & 15)][kb];
      bf16x8 a1 = *(const bf16x8*)&As[wr * 32 + 16 + (lane & 15)][kb];
      bf16x8 b0 = *(const bf16x8*)&Bs[wc * 32 +      (lane & 15)][kb];
      bf16x8 b1 = *(const bf16x8*)&Bs[wc * 32 + 16 + (lane & 15)][kb];
      acc[0][0] = __builtin_amdgcn_mfma_f32_16x16x32_bf16(a0, b0, acc[0][0], 0, 0, 0);
      acc[0][1] = __builtin_amdgcn_mfma_f32_16x16x32_bf16(a0, b1, acc[0][1], 0, 0, 0);
      acc[1][0] = __builtin_amdgcn_mfma_f32_16x16x32_bf16(a1, b0, acc[1][0], 0, 0, 0);
      acc[1][1] = __builtin_amdgcn_mfma_f32_16x16x32_bf16(a1, b1, acc[1][1], 0, 0, 0);
    }
    __syncthreads();
  }

  const int row0 = bm * 64 + wr * 32 + (lane >> 4) * 4;
  const int col0 = bn * 64 + wc * 32 + (lane & 15);
  #pragma unroll
  for (int fm = 0; fm < 2; ++fm)
    #pragma unroll
    for (int fn = 0; fn < 2; ++fn) {
      int n = col0 + fn * 16;
      float bv = bias[n];
      #pragma unroll
      for (int reg = 0; reg < 4; ++reg) {
        size_t off = (size_t)(row0 + fm * 16 + reg) * G3 + n;
        store_ip<IPT>(C + off, acc[fm][fn][reg] + bv);
      }
    }
}

// ---------------------------------------------------------------------------
// fused recurrence: WG 0..15 layer 0, WG 16..31 layer 1.
// Lane (wave=(mh,set), hi=lane>>4, jj=lane&15) owns batch bb = set*16+jj and
// cols cc0..cc0+3, cc0 = p*32 + mh*16 + hi*4, for all 3 gates.
// ---------------------------------------------------------------------------
template <typename IPT>
__global__ __launch_bounds__(256, 1) void gru_fused(
    const IPT* __restrict__ ip0,
    const uint4* __restrict__ bfWh0,
    const float* __restrict__ bh0,
    const uint4* __restrict__ bfWh1,
    const uint4* __restrict__ bfWi1,
    const float* __restrict__ bi1,
    const float* __restrict__ bh1,
    float* __restrict__ y1,
    float* __restrict__ hlast,
    unsigned long long* __restrict__ h0buf,   // [2][32][128] 8B (f16 [32][512])
    unsigned long long* __restrict__ h1buf,   // [2][32][128] 8B
    unsigned long long* __restrict__ y0h,     // [S][32][128] 8B
    unsigned int* __restrict__ fl0,           // [S][16] per-WG flags
    unsigned int* __restrict__ fl1) {         // [S][16]
  __shared__ __align__(16) uint4 wiB[6144];   // L1 only (96 KB)
  const int bid = blockIdx.x, tid = threadIdx.x;
  const int lane = tid & 63, wave = tid >> 6;
  const int set = wave & 1, mh = wave >> 1;
  const int jj = lane & 15, hi = lane >> 4;
  const int bb = set * 16 + jj;               // this lane's batch
  const int bbyte = bb * 1024 + hi * 16;      // h B-frag byte base

  if (bid < NWG) {
    // ======================= layer 0 (byte-for-byte r10) ===================
    const int p = bid;
    const int cc0 = p * 32 + mh * 16 + hi * 4;     // this lane's col base
    uint4 wf[48];
    {
      const uint4* bsrc = bfWh0 + ((size_t)(p * 2 + mh) * 48) * 64 + lane;
      #pragma unroll
      for (int i = 0; i < 48; ++i) wf[i] = bsrc[i * 64];
      #pragma unroll
      for (int i = 0; i < 48; ++i)
        asm volatile("" : "+v"(wf[i].x), "+v"(wf[i].y), "+v"(wf[i].z), "+v"(wf[i].w));
    }
    const float4 bhr4 = *(const float4*)(bh0 + cc0);
    const float4 bhz4 = *(const float4*)(bh0 + 512 + cc0);
    const float4 bhn4 = *(const float4*)(bh0 + 1024 + cc0);
    float hfq[4] = {0.f, 0.f, 0.f, 0.f};

    for (int t = 0; t < S_LEN; ++t) {
      const IPT* bp = ip0 + ((size_t)bb * S_LEN + t) * G3 + cc0;
      float4 ipr = load_ip4<IPT>(bp);
      float4 ipz = load_ip4<IPT>(bp + 512);
      float4 ipn = load_ip4<IPT>(bp + 1024);
      __builtin_amdgcn_sched_barrier(0);

      if (t > 0) {
        const unsigned int* f = fl0 + (size_t)(t - 1) * NWG;
        while (true) {
          unsigned v = (lane < NWG)
              ? __hip_atomic_load(f + lane, __ATOMIC_RELAXED, __HIP_MEMORY_SCOPE_AGENT)
              : 1u;
          if (__all(v != 0)) break;
          __builtin_amdgcn_s_sleep(1);
        }
      }
      __builtin_amdgcn_sched_barrier(0);

      const char* hb = (const char*)h0buf + (t & 1) * 32768 + bbyte;
      uint4 bf[16];
      #pragma unroll
      for (int ks = 0; ks < 16; ++ks)
        asm volatile("global_load_dwordx4 %0, %1, off offset:%2 sc0 sc1"
                     : "=v"(bf[ks]) : "v"(hb), "i"(ks * 64) : "memory");
      asm volatile("s_waitcnt vmcnt(0)" ::: "memory");
      __builtin_amdgcn_sched_barrier(0);

      f32x4 a0 = {}, a1 = {}, a2 = {};
      #pragma unroll
      for (int ks = 0; ks < 16; ++ks) {
        f16x8 hv = __builtin_bit_cast(f16x8, bf[ks]);
        a0 = __builtin_amdgcn_mfma_f32_16x16x32_f16(__builtin_bit_cast(f16x8, wf[ks]),      hv, a0, 0, 0, 0);
        a1 = __builtin_amdgcn_mfma_f32_16x16x32_f16(__builtin_bit_cast(f16x8, wf[16 + ks]), hv, a1, 0, 0, 0);
        a2 = __builtin_amdgcn_mfma_f32_16x16x32_f16(__builtin_bit_cast(f16x8, wf[32 + ks]), hv, a2, 0, 0, 0);
      }

      unsigned short hx[4];
      #pragma unroll
      for (int q = 0; q < 4; ++q) {
        float rr = sigmoid_f(a0[q] + (&bhr4.x)[q] + (&ipr.x)[q]);
        float zz = sigmoid_f(a1[q] + (&bhz4.x)[q] + (&ipz.x)[q]);
        float nn = tanh_f((&ipn.x)[q] + rr * (a2[q] + (&bhn4.x)[q]));
        float hy = (1.f - zz) * nn + zz * hfq[q];
        hfq[q] = hy;
        hx[q] = __builtin_bit_cast(unsigned short, (_Float16)hy);
      }
      const unsigned long long hw =
          (unsigned long long)hx[0] | ((unsigned long long)hx[1] << 16) |
          ((unsigned long long)hx[2] << 32) | ((unsigned long long)hx[3] << 48);
      const size_t slot = (size_t)bb * 128 + (cc0 >> 2);
      __hip_atomic_store(h0buf + ((size_t)((t + 1) & 1)) * 4096 + slot, hw,
                         __ATOMIC_RELAXED, __HIP_MEMORY_SCOPE_AGENT);
      __hip_atomic_store(y0h + (size_t)t * 4096 + slot, hw,
                         __ATOMIC_RELAXED, __HIP_MEMORY_SCOPE_AGENT);
      asm volatile("s_waitcnt vmcnt(0)" ::: "memory");
      __syncthreads();
      if (tid == 0)
        __hip_atomic_store(fl0 + (size_t)t * NWG + p, 1u,
                           __ATOMIC_RELAXED, __HIP_MEMORY_SCOPE_AGENT);
    }
  } else {
    // ======================= layer 1 (shadow ip1) ==========================
    const int p = bid - NWG;
    const int cc0 = p * 32 + mh * 16 + hi * 4;
    uint4 wf[48];
    {
      const uint4* bsrc = bfWh1 + ((size_t)(p * 2 + mh) * 48) * 64 + lane;
      #pragma unroll
      for (int i = 0; i < 48; ++i) wf[i] = bsrc[i * 64];
      #pragma unroll
      for (int i = 0; i < 48; ++i)
        asm volatile("" : "+v"(wf[i].x), "+v"(wf[i].y), "+v"(wf[i].z), "+v"(wf[i].w));
    }
    {
      const uint4* src = bfWi1 + (size_t)p * 6144;
      for (int i = tid; i < 6144; i += 256) wiB[i] = src[i];
    }
    const float4 bir4 = *(const float4*)(bi1 + cc0);
    const float4 biz4 = *(const float4*)(bi1 + 512 + cc0);
    const float4 bin4 = *(const float4*)(bi1 + 1024 + cc0);
    const float4 bhr4 = *(const float4*)(bh1 + cc0);
    const float4 bhz4 = *(const float4*)(bh1 + 512 + cc0);
    const float4 bhn4 = *(const float4*)(bh1 + 1024 + cc0);
    float hfq[4] = {0.f, 0.f, 0.f, 0.f};
    const int wb = mh * 3072 + lane;
    __syncthreads();                          // wiB ready (once)

    // ---- shadow prologue: ip1 for t = 0 ----
    f32x4 i0 = {}, i1 = {}, i2 = {};
    {
      const unsigned int* f = fl0;            // fl0[0]
      while (true) {
        unsigned v = (lane < NWG)
            ? __hip_atomic_load(f + lane, __ATOMIC_RELAXED, __HIP_MEMORY_SCOPE_AGENT)
            : 1u;
        if (__all(v != 0)) break;
        __builtin_amdgcn_s_sleep(1);
      }
      __builtin_amdgcn_sched_barrier(0);
      uint4 ay[16];
      const char* yb = (const char*)y0h + bbyte;
      #pragma unroll
      for (int ks = 0; ks < 16; ++ks)
        asm volatile("global_load_dwordx4 %0, %1, off offset:%2 sc0 sc1"
                     : "=v"(ay[ks]) : "v"(yb), "i"(ks * 64) : "memory");
      asm volatile("s_waitcnt vmcnt(0)" ::: "memory");
      __builtin_amdgcn_sched_barrier(0);
      #pragma unroll
      for (int ks = 0; ks < 16; ++ks) {
        f16x8 yv = __builtin_bit_cast(f16x8, ay[ks]);
        i0 = __builtin_amdgcn_mfma_f32_16x16x32_f16(__builtin_bit_cast(f16x8, wiB[wb + ks * 64]),        yv, i0, 0, 0, 0);
        i1 = __builtin_amdgcn_mfma_f32_16x16x32_f16(__builtin_bit_cast(f16x8, wiB[wb + (16 + ks) * 64]), yv, i1, 0, 0, 0);
        i2 = __builtin_amdgcn_mfma_f32_16x16x32_f16(__builtin_bit_cast(f16x8, wiB[wb + (32 + ks) * 64]), yv, i2, 0, 0, 0);
      }
    }

    for (int t = 0; t < S_LEN; ++t) {
      // -- wait own h1(t-1) --
      if (t > 0) {
        const unsigned int* f = fl1 + (size_t)(t - 1) * NWG;
        while (true) {
          unsigned v = (lane < NWG)
              ? __hip_atomic_load(f + lane, __ATOMIC_RELAXED, __HIP_MEMORY_SCOPE_AGENT)
              : 1u;
          if (__all(v != 0)) break;
          __builtin_amdgcn_s_sleep(1);
        }
      }
      __builtin_amdgcn_sched_barrier(0);

      uint4 ah[16];
      {
        const char* hb = (const char*)h1buf + (t & 1) * 32768 + bbyte;
        #pragma unroll
        for (int ks = 0; ks < 16; ++ks)
          asm volatile("global_load_dwordx4 %0, %1, off offset:%2 sc0 sc1"
                       : "=v"(ah[ks]) : "v"(hb), "i"(ks * 64) : "memory");
        asm volatile("s_waitcnt vmcnt(0)" ::: "memory");
      }
      __builtin_amdgcn_sched_barrier(0);

      f32x4 c0 = {}, c1 = {}, c2 = {};
      #pragma unroll
      for (int ks = 0; ks < 16; ++ks) {
        f16x8 hv = __builtin_bit_cast(f16x8, ah[ks]);
        c0 = __builtin_amdgcn_mfma_f32_16x16x32_f16(__builtin_bit_cast(f16x8, wf[ks]),      hv, c0, 0, 0, 0);
        c1 = __builtin_amdgcn_mfma_f32_16x16x32_f16(__builtin_bit_cast(f16x8, wf[16 + ks]), hv, c1, 0, 0, 0);
        c2 = __builtin_amdgcn_mfma_f32_16x16x32_f16(__builtin_bit_cast(f16x8, wf[32 + ks]), hv, c2, 0, 0, 0);
      }

      // -- gates in-register (ip1 precomputed); publish h1 (one 8B store) --
      float hyv[4];
      unsigned short hx[4];
      #pragma unroll
      for (int q = 0; q < 4; ++q) {
        float rr = sigmoid_f(i0[q] + c0[q] + (&bir4.x)[q] + (&bhr4.x)[q]);
        float zz = sigmoid_f(i1[q] + c1[q] + (&biz4.x)[q] + (&bhz4.x)[q]);
        float nn = tanh_f((i2[q] + (&bin4.x)[q]) + rr * (c2[q] + (&bhn4.x)[q]));
        float hy = (1.f - zz) * nn + zz * hfq[q];
        hfq[q] = hy;
        hyv[q] = hy;
        hx[q] = __builtin_bit_cast(unsigned short, (_Float16)hy);
      }
      const unsigned long long hw =
          (unsigned long long)hx[0] | ((unsigned long long)hx[1] << 16) |
          ((unsigned long long)hx[2] << 32) | ((unsigned long long)hx[3] << 48);
      __hip_atomic_store(h1buf + ((size_t)((t + 1) & 1)) * 4096 + (size_t)bb * 128 + (cc0 >> 2),
                         hw, __ATOMIC_RELAXED, __HIP_MEMORY_SCOPE_AGENT);
      asm volatile("s_waitcnt vmcnt(0)" ::: "memory");
      __syncthreads();
      if (tid == 0)
        __hip_atomic_store(fl1 + (size_t)t * NWG + p, 1u,
                           __ATOMIC_RELAXED, __HIP_MEMORY_SCOPE_AGENT);

      // -- y1 float4 store, off the critical path --
      float4 yo = { hyv[0], hyv[1], hyv[2], hyv[3] };
      *(float4*)(y1 + ((size_t)bb * S_LEN + t) * HID + cc0) = yo;
      if (t == S_LEN - 1)
        *(float4*)(hlast + (size_t)bb * HID + cc0) = yo;

      // -- shadow: ip1 for step t+1 (overlaps other L1 WGs' step t) --
      if (t + 1 < S_LEN) {
        const unsigned int* f = fl0 + (size_t)(t + 1) * NWG;
        while (true) {
          unsigned v = (lane < NWG)
              ? __hip_atomic_load(f + lane, __ATOMIC_RELAXED, __HIP_MEMORY_SCOPE_AGENT)
              : 1u;
          if (__all(v != 0)) break;
          __builtin_amdgcn_s_sleep(1);
        }
        __builtin_amdgcn_sched_barrier(0);
        uint4 ay[16];
        const char* yb = (const char*)y0h + (size_t)(t + 1) * 32768 + bbyte;
        #pragma unroll
        for (int ks = 0; ks < 16; ++ks)
          asm volatile("global_load_dwordx4 %0, %1, off offset:%2 sc0 sc1"
                       : "=v"(ay[ks]) : "v"(yb), "i"(ks * 64) : "memory");
        asm volatile("s_waitcnt vmcnt(0)" ::: "memory");
        __builtin_amdgcn_sched_barrier(0);
        i0 = {}; i1 = {}; i2 = {};
        #pragma unroll
        for (int ks = 0; ks < 16; ++ks) {
          f16x8 yv = __builtin_bit_cast(f16x8, ay[ks]);
          i0 = __builtin_amdgcn_mfma_f32_16x16x32_f16(__builtin_bit_cast(f16x8, wiB[wb + ks * 64]),        yv, i0, 0, 0, 0);
          i1 = __builtin_amdgcn_mfma_f32_16x16x32_f16(__builtin_bit_cast(f16x8, wiB[wb + (16 + ks) * 64]), yv, i1, 0, 0, 0);
          i2 = __builtin_amdgcn_mfma_f32_16x16x32_f16(__builtin_bit_cast(f16x8, wiB[wb + (32 + ks) * 64]), yv, i2, 0, 0, 0);
        }
      }
    }
  }
}

// ---------------------------------------------------------------------------
// ws layout (bytes)
// ---------------------------------------------------------------------------
#define BFWH0_OFF 0ull
#define BFWH1_OFF 1572864ull
#define BFWI1_OFF 3145728ull
#define WI0_OFF   4718592ull
#define H0_OFF    6291456ull      // 65536
#define H1_OFF    6356992ull      // 65536
#define FL0_OFF   6422528ull      // 131072 ([2048][16] dwords)
#define FL1_OFF   6553600ull      // 131072
#define Y0H_OFF   6684672ull      // 67108864
#define IP_OFF    73793536ull

template <typename IPT>
static void run_all(const float* x,
                    const float* Wi0, const float* bi0, const float* Wh0, const float* bh0,
                    const float* Wi1, const float* bi1, const float* Wh1, const float* bh1,
                    float* out, char* ws, hipStream_t stream) {
  unsigned int* bfWh0 = (unsigned int*)(ws + BFWH0_OFF);
  unsigned int* bfWh1 = (unsigned int*)(ws + BFWH1_OFF);
  unsigned int* bfWi1 = (unsigned int*)(ws + BFWI1_OFF);
  __bf16* wi0b = (__bf16*)(ws + WI0_OFF);
  unsigned long long* h0buf = (unsigned long long*)(ws + H0_OFF);
  unsigned long long* h1buf = (unsigned long long*)(ws + H1_OFF);
  unsigned int* fl0 = (unsigned int*)(ws + FL0_OFF);
  unsigned int* fl1 = (unsigned int*)(ws + FL1_OFF);
  unsigned long long* y0h = (unsigned long long*)(ws + Y0H_OFF);
  IPT* ip = (IPT*)(ws + IP_OFF);
  float* y1    = out;
  float* hlast = out + (size_t)MROWS * HID;

  // zero h bufs + both flag arrays (contiguous region) each launch
  hipMemsetAsync(ws + H0_OFF, 0, 65536 + 65536 + 131072 + 131072, stream);

  prep_bfrag<<<dim3(1536), dim3(256), 0, stream>>>(Wh0, bfWh0);
  prep_bfrag<<<dim3(1536), dim3(256), 0, stream>>>(Wh1, bfWh1);
  prep_bfrag<<<dim3(1536), dim3(256), 0, stream>>>(Wi1, bfWi1);
  prep_wib<<<dim3(3072), dim3(256), 0, stream>>>(Wi0, wi0b);

  gemm_ip<IPT><<<dim3(24, 1024), dim3(256), 0, stream>>>(x, wi0b, bi0, ip);
  gru_fused<IPT><<<dim3(2 * NWG), dim3(256), 0, stream>>>(
      ip, (const uint4*)bfWh0, bh0, (const uint4*)bfWh1, (const uint4*)bfWi1,
      bi1, bh1, y1, hlast, h0buf, h1buf, y0h, fl0, fl1);
}

extern "C" void kernel_launch(void* const* d_in, const int* in_sizes, int n_in,
                              void* d_out, int out_size, void* d_ws, size_t ws_size,
                              hipStream_t stream) {
  const float* x   = (const float*)d_in[0];
  const float* Wi0 = (const float*)d_in[1];
  const float* bi0 = (const float*)d_in[2];
  const float* Wh0 = (const float*)d_in[3];
  const float* bh0 = (const float*)d_in[4];
  const float* Wi1 = (const float*)d_in[5];
  const float* bi1 = (const float*)d_in[6];
  const float* Wh1 = (const float*)d_in[7];
  const float* bh1 = (const float*)d_in[8];
  float* out = (float*)d_out;
  char*  ws  = (char*)d_ws;

  const size_t need_f32 = IP_OFF + (size_t)MROWS * G3 * 4;
  if (ws_size >= need_f32) {
    run_all<float>(x, Wi0, bi0, Wh0, bh0, Wi1, bi1, Wh1, bh1, out, ws, stream);
  } else {
    run_all<unsigned short>(x, Wi0, bi0, Wh0, bh0, Wi1, bi1, Wh1, bh1, out, ws, stream);
  }
}